// Round 12
// baseline (274.209 us; speedup 1.0000x reference)
//
#include <hip/hip_runtime.h>
#include <hip/hip_bf16.h>
#include <math.h>

// Transformer block B=2 T=2048 C=1024 H=16 HS=64.
// R12: QKV GEMM -> 256x256 tile, BK=64, 8 waves, m201-style schedule:
//  dbuf 128KB LDS, st_16x32 swizzle (pre-swizzled gl_lds source + swizzled
//  ds_read), 4 quadrant-phases per K-tile with half-tile staging spread,
//  counted vmcnt(2) (never 0 mid-loop), 2 s_barriers per K-tile, XCD-chunked
//  block decode. Attention/other GEMMs identical to R11 (absmax-verified).
//  Weight-prep kernels merged into one.

#define B_   2
#define T_   2048
#define C_   1024
#define H_   16
#define HS_  64
#define NROWS 4096
#define C3   3072
#define K1C  0.1803368801111244f    // 0.125 * log2(e), folded into Q

typedef unsigned short ushort_t;
typedef __attribute__((ext_vector_type(8))) short short8;
typedef __attribute__((ext_vector_type(4))) float f32x4;
typedef __attribute__((ext_vector_type(16))) float f32x16;

__device__ __forceinline__ ushort_t f2bf(float f) {
  __hip_bfloat16 h = __float2bfloat16(f);
  ushort_t u; __builtin_memcpy(&u, &h, 2); return u;
}
__device__ __forceinline__ float bf2f(ushort_t u) {
  union { unsigned u; float f; } v; v.u = ((unsigned)u) << 16;
  return v.f;
}
__device__ __forceinline__ unsigned pk2(float a, float b) {
  __hip_bfloat162 t = __float22bfloat162_rn(make_float2(a, b));
  unsigned u; __builtin_memcpy(&u, &t, 4); return u;
}
__device__ __forceinline__ short8 mk8(unsigned a, unsigned b, unsigned c, unsigned d) {
  union { unsigned u[4]; short8 s; } t;
  t.u[0] = a; t.u[1] = b; t.u[2] = c; t.u[3] = d; return t.s;
}
__device__ __forceinline__ void pl32swap(unsigned &a, unsigned &b) {
  asm("v_permlane32_swap_b32 %0, %1" : "+v"(a), "+v"(b));
}
__device__ __forceinline__ f32x4 mfma16(short8 a, short8 b, f32x4 c) {
  return __builtin_amdgcn_mfma_f32_16x16x32_bf16(a, b, c, 0, 0, 0);
}
__device__ __forceinline__ f32x16 mfma32(short8 a, short8 b, f32x16 c) {
  return __builtin_amdgcn_mfma_f32_32x32x16_bf16(a, b, c, 0, 0, 0);
}
typedef const __attribute__((address_space(1))) void g_void;
typedef __attribute__((address_space(3))) void l_void;
__device__ __forceinline__ void gl_lds16(const void* g, void* l) {
  __builtin_amdgcn_global_load_lds((g_void*)g, (l_void*)l, 16, 0, 0);
}

// ---------------- LayerNorm (f32 in -> bf16 out) ----------------
__global__ __launch_bounds__(256) void ln_bf16(
    const float* __restrict__ x, const float* __restrict__ g,
    const float* __restrict__ b, ushort_t* __restrict__ out) {
  int row = blockIdx.x;
  const float* xr = x + (size_t)row * C_;
  int t = threadIdx.x;
  float4 v = ((const float4*)xr)[t];
  float s  = v.x + v.y + v.z + v.w;
  float ss = v.x*v.x + v.y*v.y + v.z*v.z + v.w*v.w;
  #pragma unroll
  for (int off = 32; off > 0; off >>= 1) {
    s  += __shfl_down(s, off);
    ss += __shfl_down(ss, off);
  }
  __shared__ float red[2][4];
  int wid = t >> 6, lane = t & 63;
  if (lane == 0) { red[0][wid] = s; red[1][wid] = ss; }
  __syncthreads();
  if (t == 0) {
    float a = 0, c = 0;
    for (int i = 0; i < 4; i++) { a += red[0][i]; c += red[1][i]; }
    red[0][0] = a; red[1][0] = c;
  }
  __syncthreads();
  float mean = red[0][0] * (1.0f / C_);
  float var  = red[1][0] * (1.0f / C_) - mean * mean;
  float r = rsqrtf(var + 1e-5f);
  float4 gv = ((const float4*)g)[t];
  float4 bv = ((const float4*)b)[t];
  ushort4 o;
  o.x = f2bf((v.x - mean) * r * gv.x + bv.x);
  o.y = f2bf((v.y - mean) * r * gv.y + bv.y);
  o.z = f2bf((v.z - mean) * r * gv.z + bv.z);
  o.w = f2bf((v.w - mean) * r * gv.w + bv.w);
  ((ushort4*)(out + (size_t)row * C_))[t] = o;
}

// ---- merged weight prep: Wq/Wk/Wv -> (3072,1024) bf16 N-major;
//      Wo/W1/W2 -> three (N,K) bf16 blocks; bias concat ----
__global__ __launch_bounds__(256) void prep_weights(
    const float* __restrict__ Wq, const float* __restrict__ Wk,
    const float* __restrict__ Wv, const float* __restrict__ Wo,
    const float* __restrict__ W1, const float* __restrict__ W2,
    const float* __restrict__ bq, const float* __restrict__ bk,
    const float* __restrict__ bv, ushort_t* __restrict__ Wqkvt,
    ushort_t* __restrict__ Wot3, float* __restrict__ bqkv) {
  int bid = blockIdx.x;
  if (bid < 12288) {
    int idx = bid * 256 + threadIdx.x;
    int n = idx >> 10, c = idx & 1023;
    int sel = n >> 10, nn = n & 1023;
    const float* W = (sel == 0) ? Wq : ((sel == 1) ? Wk : Wv);
    Wqkvt[idx] = f2bf(W[((size_t)(nn >> 6) * C_ + c) * HS_ + (nn & 63)]);
  } else if (bid < 24576) {
    int idx = (bid - 12288) * 256 + threadIdx.x;
    int sel = idx >> 20, rem = idx & 1048575;
    int n = rem >> 10, k = rem & 1023;
    const float* W = (sel == 0) ? Wo : ((sel == 1) ? W1 : W2);
    Wot3[idx] = f2bf(W[(size_t)k * C_ + n]);
  } else {
    int i = (bid - 24576) * 256 + threadIdx.x;
    if (i < 3072)
      bqkv[i] = (i < 1024) ? bq[i] : ((i < 2048) ? bk[i - 1024] : bv[i - 2048]);
  }
}

// -------- QKV GEMM: 256x256 tile, BK=64, 8 waves, m201-style schedule -----
// A (4096x1024) bf16, Bt (3072x1024) bf16 N-major. Q third scaled by K1C.
#define QUADP(p) { \
  short8 af[4][2], bfr[2][2]; \
  _Pragma("unroll") \
  for (int mi = 0; mi < 4; mi++) { \
    _Pragma("unroll") \
    for (int kk = 0; kk < 2; kk++) { \
      int LA = ((((p) >> 1) * 4 + mi) * 16 + lo) * 128 + (kk * 32 + hi * 8) * 2; \
      int SA = LA ^ (((LA >> 9) & 1) << 5); \
      af[mi][kk] = *(const short8*)(Abase + SA); \
    } } \
  _Pragma("unroll") \
  for (int nj = 0; nj < 2; nj++) { \
    _Pragma("unroll") \
    for (int kk = 0; kk < 2; kk++) { \
      int LB = ((wn & 1) * 64 + (((p) & 1) * 2 + nj) * 16 + lo) * 128 + (kk * 32 + hi * 8) * 2; \
      int SB = LB ^ (((LB >> 9) & 1) << 5); \
      bfr[nj][kk] = *(const short8*)(Bbase + SB); \
    } } \
  _Pragma("unroll") \
  for (int mi = 0; mi < 4; mi++) \
    _Pragma("unroll") \
    for (int nj = 0; nj < 2; nj++) \
      _Pragma("unroll") \
      for (int kk = 0; kk < 2; kk++) \
        acc[((p) >> 1) * 4 + mi][((p) & 1) * 2 + nj] = \
          mfma16(af[mi][kk], bfr[nj][kk], acc[((p) >> 1) * 4 + mi][((p) & 1) * 2 + nj]); \
}

__global__ __launch_bounds__(512) void gemm_qkv256(
    const ushort_t* __restrict__ A, const ushort_t* __restrict__ Bt,
    const float* __restrict__ bias, ushort_t* __restrict__ Cm) {
  __shared__ ushort_t AsB[2][2][128 * 64];   // [buf][half][row*64+k] 64KB
  __shared__ ushort_t BsB[2][2][128 * 64];   // 64KB
  int t = threadIdx.x;
  int bid = blockIdx.x;
  // XCD chunking: 192 blocks -> 8 chunks of (4 mb x 6 nb)
  int chunk = bid & 7, idx = bid >> 3;
  int mb = (chunk >> 1) * 4 + (idx & 3);
  int nb = (chunk & 1) * 6 + (idx >> 2);
  int m0 = mb * 256, n0 = nb * 256;
  int w = t >> 6, l = t & 63, lo = l & 15, hi = l >> 4;
  int wm = w >> 2, wn = w & 3;

  // staging source precompute: dest byte d = i*8192 + t*16 (linear),
  // content = unswizzled position d' = d ^ (((d>>9)&1)<<5)
  int srcrow[2], srck[2];
  #pragma unroll
  for (int i = 0; i < 2; i++) {
    int d = i * 8192 + t * 16;
    int dp = d ^ (((d >> 9) & 1) << 5);
    srcrow[i] = dp >> 7;
    srck[i] = (dp & 127) >> 1;
  }
  auto stageA = [&](int buf, int h, int kt) {
    #pragma unroll
    for (int i = 0; i < 2; i++)
      gl_lds16(A + (size_t)(m0 + h * 128 + srcrow[i]) * 1024 + kt * 64 + srck[i],
               &AsB[buf][h][i * 4096 + t * 8]);
  };
  auto stageB = [&](int buf, int h, int kt) {
    #pragma unroll
    for (int i = 0; i < 2; i++)
      gl_lds16(Bt + (size_t)(n0 + h * 128 + srcrow[i]) * 1024 + kt * 64 + srck[i],
               &BsB[buf][h][i * 4096 + t * 8]);
  };

  f32x4 acc[8][4] = {};
  stageA(0, 0, 0); stageA(0, 1, 0); stageB(0, 0, 0); stageB(0, 1, 0);
  for (int kt = 0; kt < 16; kt++) {
    int cur = kt & 1, nxt = cur ^ 1;
    bool pre = (kt + 1 < 16);
    const char* Abase = (const char*)&AsB[cur][wm][0];
    const char* Bbase = (const char*)&BsB[cur][wn >> 1][0];
    if (pre) {
      stageA(nxt, 0, kt + 1);
      asm volatile("s_waitcnt vmcnt(2)");
    } else {
      asm volatile("s_waitcnt vmcnt(0)");
    }
    __builtin_amdgcn_s_barrier();
    __builtin_amdgcn_sched_barrier(0);
    QUADP(0)
    __builtin_amdgcn_sched_barrier(0);
    if (pre) stageA(nxt, 1, kt + 1);
    QUADP(1)
    __builtin_amdgcn_sched_barrier(0);
    if (pre) stageB(nxt, 0, kt + 1);
    QUADP(2)
    __builtin_amdgcn_sched_barrier(0);
    if (pre) stageB(nxt, 1, kt + 1);
    QUADP(3)
    __builtin_amdgcn_sched_barrier(0);
    __builtin_amdgcn_s_barrier();
  }

  #pragma unroll
  for (int i = 0; i < 8; i++) {
    int mrow = m0 + wm * 128 + i * 16 + hi * 4;
    #pragma unroll
    for (int j = 0; j < 4; j++) {
      int col = n0 + wn * 64 + j * 16 + lo;
      float bv = bias[col];
      float qs = (n0 + wn * 64 + j * 16 < 1024) ? K1C : 1.0f;
      #pragma unroll
      for (int r = 0; r < 4; r++)
        Cm[(size_t)(mrow + r) * C3 + col] = f2bf((acc[i][j][r] + bv) * qs);
    }
  }
}

// ---------------- GEMM 128x64 tile (N=1024 GEMMs) ----------------
template<int OUT_BF16, int RELU, int HAS_RES>
__global__ __launch_bounds__(256) void gemm64(
    const ushort_t* __restrict__ A, const ushort_t* __restrict__ Bt,
    const float* __restrict__ bias, const float* __restrict__ res,
    void* __restrict__ Cm, int M, int N, int K) {
  __shared__ ushort_t As[128 * 32];
  __shared__ ushort_t Bs[64 * 32];
  int t = threadIdx.x;
  int m0 = blockIdx.y * 128, n0 = blockIdx.x * 64;
  int w = t >> 6, l = t & 63;
  int wr = w >> 1, wc = w & 1;
  int lo = l & 15, hi = l >> 4;
  f32x4 acc[4][2] = {};
  int srow = t >> 2, scol = (t & 3) * 8;
  const ushort_t* Ag = A  + (size_t)(m0 + srow) * K + scol;
  const ushort_t* Bg = Bt + (size_t)(n0 + srow) * K + scol;
  ushort_t* AsP = As + t * 8;
  ushort_t* BsP = Bs + t * 8;
  for (int k0 = 0; k0 < K; k0 += 32) {
    gl_lds16(Ag + k0,          AsP);
    gl_lds16(Ag + 64 * K + k0, AsP + 64 * 32);
    gl_lds16(Bg + k0,          BsP);
    __syncthreads();
    short8 af[4], bfr[2];
    #pragma unroll
    for (int i = 0; i < 4; i++)
      af[i] = *(const short8*)&As[(wr * 64 + i * 16 + lo) * 32 + hi * 8];
    #pragma unroll
    for (int j = 0; j < 2; j++)
      bfr[j] = *(const short8*)&Bs[(wc * 32 + j * 16 + lo) * 32 + hi * 8];
    #pragma unroll
    for (int i = 0; i < 4; i++)
      #pragma unroll
      for (int j = 0; j < 2; j++)
        acc[i][j] = mfma16(af[i], bfr[j], acc[i][j]);
    __syncthreads();
  }
  #pragma unroll
  for (int i = 0; i < 4; i++) {
    int m = m0 + wr * 64 + i * 16 + hi * 4;
    #pragma unroll
    for (int j = 0; j < 2; j++) {
      int n = n0 + wc * 32 + j * 16 + lo;
      float bv = bias[n];
      #pragma unroll
      for (int r = 0; r < 4; r++) {
        float v = acc[i][j][r] + bv;
        if (HAS_RES) v += res[(size_t)(m + r) * N + n];
        if (RELU) v = fmaxf(v, 0.f);
        if (OUT_BF16) ((ushort_t*)Cm)[(size_t)(m + r) * N + n] = f2bf(v);
        else          ((float*)Cm)[(size_t)(m + r) * N + n] = v;
      }
    }
  }
}

// ---- stats: 4 waves x 32 k-rows, Q tiles 3-buffered. XCD-pinned grid ----
__global__ __launch_bounds__(256) void attn_stats(
    const ushort_t* __restrict__ QKV, float* __restrict__ dinv) {
  int bid = blockIdx.x;
  int xcd = bid & 7, q = bid >> 3;
  int bh = xcd * 4 + (q & 3);
  int kb = q >> 2;
  int b = bh >> 4, h = bh & 15;
  int t = threadIdx.x, w = t >> 6, l = t & 63, l31 = l & 31, hi32 = l >> 5;
  __shared__ ushort_t Qs[3][32 * 64];
  const ushort_t* Qb = QKV + (size_t)b * T_ * C3 + h * HS_;
  const ushort_t* Kb = Qb + C_;
  int k0w = kb * 128 + w * 32;
  short8 ka[4];
  #pragma unroll
  for (int c = 0; c < 4; c++)
    ka[c] = *(const short8*)(Kb + (size_t)(k0w + l31) * C3 + c * 16 + hi32 * 8);
  float s[16];
  #pragma unroll
  for (int r = 0; r < 16; r++) s[r] = 0.f;

  int sr = t >> 3, slot = t & 7, su = slot ^ (sr & 7);
  const ushort_t* Qsrc = Qb + (size_t)sr * C3 + su * 8;
  int qt0 = kb * 4, cnt = 64 - qt0;
  int dqt = qt0 + w;

  gl_lds16(Qsrc + (size_t)qt0 * 32 * C3, &Qs[0][t * 8]);
  if (cnt > 1) gl_lds16(Qsrc + (size_t)(qt0 + 1) * 32 * C3, &Qs[1][t * 8]);
  for (int i = 0; i < cnt; i++) {
    int qt = qt0 + i;
    int cur = i % 3;
    if (i + 2 < cnt) {
      gl_lds16(Qsrc + (size_t)(qt + 2) * 32 * C3, &Qs[(i + 2) % 3][t * 8]);
      asm volatile("s_waitcnt vmcnt(2)");
    } else if (i + 1 < cnt) {
      asm volatile("s_waitcnt vmcnt(1)");
    } else {
      asm volatile("s_waitcnt vmcnt(0)");
    }
    __builtin_amdgcn_s_barrier();
    __builtin_amdgcn_sched_barrier(0);
    if (qt >= dqt) {
      short8 qf[4];
      #pragma unroll
      for (int c = 0; c < 4; c++)
        qf[c] = *(const short8*)&Qs[cur][l31 * 64 + ((c * 2 + hi32) ^ (l31 & 7)) * 8];
      f32x16 d = {};
      #pragma unroll
      for (int c = 0; c < 4; c++) d = mfma32(ka[c], qf[c], d);
      if (qt == dqt) {
        int qq = qt * 32 + l31;
        #pragma unroll
        for (int r = 0; r < 16; r++) {
          int k = k0w + (r & 3) + 8 * (r >> 2) + 4 * hi32;
          s[r] += (qq >= k) ? exp2f(d[r]) : 0.f;
        }
      } else {
        #pragma unroll
        for (int r = 0; r < 16; r++) s[r] += exp2f(d[r]);
      }
    }
    __builtin_amdgcn_sched_barrier(0);
    __builtin_amdgcn_s_barrier();
    __builtin_amdgcn_sched_barrier(0);
  }
  #pragma unroll
  for (int off = 1; off < 32; off <<= 1)
    #pragma unroll
    for (int r = 0; r < 16; r++)
      s[r] += __shfl_xor(s[r], off);
  if (l31 == 0) {
    #pragma unroll
    for (int r = 0; r < 16; r++) {
      int k = k0w + (r & 3) + 8 * (r >> 2) + 4 * hi32;
      dinv[(size_t)bh * T_ + k] = 1.0f / s[r];
    }
  }
}

// ---- V' = V * dinv, per-head transpose to (bh, HS, T) ----
__global__ __launch_bounds__(256) void transpose_v(
    const ushort_t* __restrict__ QKV, const float* __restrict__ dinv,
    ushort_t* __restrict__ Vt) {
  int t0 = blockIdx.x * 64;
  int bh = blockIdx.y; int b = bh >> 4, h = bh & 15;
  __shared__ ushort_t tile[64][65];
  int tid = threadIdx.x;
  #pragma unroll
  for (int i = 0; i < 16; i++) {
    int idx = i * 256 + tid;
    int tt = idx >> 6, dd = idx & 63;
    float v = bf2f(QKV[(size_t)(b * T_ + t0 + tt) * C3 + 2 * C_ + h * HS_ + dd]);
    tile[tt][dd] = f2bf(v * dinv[(size_t)bh * T_ + t0 + tt]);
  }
  __syncthreads();
  #pragma unroll
  for (int i = 0; i < 16; i++) {
    int idx = i * 256 + tid;
    int dd = idx >> 6, tt = idx & 63;
    Vt[((size_t)(bh * HS_ + dd)) * T_ + t0 + tt] = tile[tt][dd];
  }
}

// ---- PV: 4 waves x 32 q-rows, K/V' 3-buffered. XCD-pinned grid ----
__global__ __launch_bounds__(256) void attn_pv(
    const ushort_t* __restrict__ QKV, const ushort_t* __restrict__ Vt,
    ushort_t* __restrict__ att) {
  int bid = blockIdx.x;
  int xcd = bid & 7, q = bid >> 3;
  int bh = xcd * 4 + (q & 3);
  int qb = 15 - (q >> 2);
  int b = bh >> 4, h = bh & 15;
  int t = threadIdx.x, w = t >> 6, l = t & 63, l31 = l & 31, hi32 = l >> 5;
  __shared__ ushort_t Ks[3][32 * 64];
  __shared__ ushort_t Vs[3][32 * 64];
  const ushort_t* Qb = QKV + (size_t)b * T_ * C3 + h * HS_;
  const ushort_t* Kb = Qb + C_;
  const ushort_t* Vb = Vt + (size_t)bh * HS_ * T_;
  int q0w = qb * 128 + w * 32;
  short8 qf[4];
  #pragma unroll
  for (int c = 0; c < 4; c++)
    qf[c] = *(const short8*)(Qb + (size_t)(q0w + l31) * C3 + c * 16 + hi32 * 8);
  f32x16 o0 = {}, o1 = {};
  int nkt = qb * 4 + 4;
  int dkt = q0w >> 5;

  int sr = t >> 3, slot = t & 7, su = slot ^ (sr & 7);
  int vdh = su >> 2, vc2 = su & 3;
  const ushort_t* Ksrc = Kb + (size_t)sr * C3 + su * 8;
  const ushort_t* Vsrc = Vb + (size_t)(vdh * 32 + sr) * T_ + vc2 * 8;

  gl_lds16(Ksrc, &Ks[0][t * 8]);
  gl_lds16(Vsrc, &Vs[0][t * 8]);
  if (nkt > 1) {
    gl_lds16(Ksrc + (size_t)32 * C3, &Ks[1][t * 8]);
    gl_lds16(Vsrc + 32,              &Vs[1][t * 8]);
  }
  for (int kt = 0; kt < nkt; kt++) {
    int cur = kt % 3;
    if (kt + 2 < nkt) {
      gl_lds16(Ksrc + (size_t)(kt + 2) * 32 * C3, &Ks[(kt + 2) % 3][t * 8]);
      gl_lds16(Vsrc + (kt + 2) * 32,              &Vs[(kt + 2) % 3][t * 8]);
      asm volatile("s_waitcnt vmcnt(4)");
    } else if (kt + 1 < nkt) {
      asm volatile("s_waitcnt vmcnt(2)");
    } else {
      asm volatile("s_waitcnt vmcnt(0)");
    }
    __builtin_amdgcn_s_barrier();
    __builtin_amdgcn_sched_barrier(0);
    if (kt <= dkt) {
      short8 ka[4], vf[4];
      #pragma unroll
      for (int c = 0; c < 4; c++)
        ka[c] = *(const short8*)&Ks[cur][l31 * 64 + ((c * 2 + hi32) ^ (l31 & 7)) * 8];
      #pragma unroll
      for (int i = 0; i < 4; i++) {
        int u = (i & 1) * 4 + (i >> 1) * 2 + hi32;
        vf[i] = *(const short8*)&Vs[cur][l31 * 64 + (u ^ (l31 & 7)) * 8];
      }
      f32x16 sacc = {};
      #pragma unroll
      for (int c = 0; c < 4; c++) sacc = mfma32(ka[c], qf[c], sacc);
      float e[16];
      if (kt == dkt) {
        int qq = q0w + l31;
        #pragma unroll
        for (int r = 0; r < 16; r++) {
          int k = kt * 32 + (r & 3) + 8 * (r >> 2) + 4 * hi32;
          e[r] = (k <= qq) ? exp2f(sacc[r]) : 0.f;
        }
      } else {
        #pragma unroll
        for (int r = 0; r < 16; r++) e[r] = exp2f(sacc[r]);
      }
      unsigned u[8];
      #pragma unroll
      for (int j = 0; j < 8; j++) u[j] = pk2(e[2 * j], e[2 * j + 1]);
      pl32swap(u[0], u[2]); pl32swap(u[1], u[3]);
      pl32swap(u[4], u[6]); pl32swap(u[5], u[7]);
      short8 pa0 = mk8(u[0], u[1], u[2], u[3]);
      short8 pa1 = mk8(u[4], u[5], u[6], u[7]);
      o0 = mfma32(pa0, vf[0], o0);
      o1 = mfma32(pa0, vf[1], o1);
      o0 = mfma32(pa1, vf[2], o0);
      o1 = mfma32(pa1, vf[3], o1);
    }
    __builtin_amdgcn_sched_barrier(0);
    __builtin_amdgcn_s_barrier();
    __builtin_amdgcn_sched_barrier(0);
  }

  #pragma unroll
  for (int r = 0; r < 16; r++) {
    int qq = q0w + (r & 3) + 8 * (r >> 2) + 4 * hi32;
    size_t base = (size_t)(b * T_ + qq) * C_ + h * HS_;
    att[base + l31]      = f2bf(o0[r]);
    att[base + 32 + l31] = f2bf(o1[r]);
  }
}

extern "C" void kernel_launch(void* const* d_in, const int* in_sizes, int n_in,
                              void* d_out, int out_size, void* d_ws, size_t ws_size,
                              hipStream_t stream) {
  const float* x   = (const float*)d_in[0];
  const float* Wq  = (const float*)d_in[1];
  const float* bq  = (const float*)d_in[2];
  const float* Wk  = (const float*)d_in[3];
  const float* bk  = (const float*)d_in[4];
  const float* Wv  = (const float*)d_in[5];
  const float* bv  = (const float*)d_in[6];
  const float* Wo  = (const float*)d_in[7];
  const float* bo  = (const float*)d_in[8];
  const float* g1  = (const float*)d_in[9];
  const float* b1  = (const float*)d_in[10];
  const float* g2  = (const float*)d_in[11];
  const float* b2  = (const float*)d_in[12];
  const float* W1  = (const float*)d_in[13];
  const float* bf1 = (const float*)d_in[14];
  const float* W2  = (const float*)d_in[15];
  const float* bf2 = (const float*)d_in[16];
  float* out = (float*)d_out;

  char* base = (char*)d_ws;
  const size_t MB = 1 << 20;
  ushort_t* QKVb  = (ushort_t*)(base);            // 24MB
  ushort_t* hb    = (ushort_t*)(base + 24 * MB);  // 8MB: LN1 out -> att
  ushort_t* Vt    = (ushort_t*)(base + 32 * MB);  // 8MB: V' -> f1b
  float*    y     = (float*)   (base + 40 * MB);  // 16MB
  ushort_t* Wqkvt = (ushort_t*)(base + 56 * MB);  // 6MB
  ushort_t* Wot   = (ushort_t*)(base + 62 * MB);  // 2MB (Wo,W1,W2 contiguous)
  ushort_t* W1t   = (ushort_t*)(base + 64 * MB);
  ushort_t* W2t   = (ushort_t*)(base + 66 * MB);
  float*    bqkv  = (float*)   (base + 68 * MB);  // 12KB
  float*    dinv  = (float*)   (base + 68 * MB + 65536); // 256KB

  prep_weights<<<24588, 256, 0, stream>>>(Wq, Wk, Wv, Wo, W1, W2,
                                          bq, bk, bv, Wqkvt, Wot, bqkv);

  ln_bf16<<<NROWS, 256, 0, stream>>>(x, g1, b1, hb);

  gemm_qkv256<<<192, 512, 0, stream>>>(hb, Wqkvt, bqkv, QKVb);

  attn_stats<<<512, 256, 0, stream>>>(QKVb, dinv);
  transpose_v<<<dim3(T_ / 64, 32), 256, 0, stream>>>(QKVb, dinv, Vt);
  ushort_t* attb = hb;
  attn_pv<<<512, 256, 0, stream>>>(QKVb, Vt, attb);

  dim3 g64(C_ / 64, NROWS / 128);
  gemm64<0,0,1><<<g64, 256, 0, stream>>>(attb, Wot, bo, x, y, NROWS, C_, C_);

  ushort_t* h2b = QKVb;
  ln_bf16<<<NROWS, 256, 0, stream>>>(y, g2, b2, h2b);
  ushort_t* f1b = Vt;
  gemm64<1,1,0><<<g64, 256, 0, stream>>>(h2b, W1t, bf1, nullptr, f1b, NROWS, C_, C_);
  gemm64<0,0,1><<<g64, 256, 0, stream>>>(f1b, W2t, bf2, y, out, NROWS, C_, C_);
}

// Round 13
// 272.454 us; speedup vs baseline: 1.0064x; 1.0064x over previous
//
#include <hip/hip_runtime.h>
#include <hip/hip_bf16.h>
#include <math.h>

// Transformer block B=2 T=2048 C=1024 H=16 HS=64.
// R13: (1) balanced complementary block pairing for attn pv/stats (each CU
// gets a big+small pair = constant 68 iters -> 2 blocks/CU sustained),
// (2) all GEMMs on the proven 128x128 2-barrier structure (unified gemmT),
// (3) T5 setprio around MFMA clusters in attention.
// Column-softmax (query-axis quirk), exp2-only (Q pre-scaled by K1C in QKV
// epilogue), dinv folded into V'. Math identical to R9-R12 (absmax-verified).

#define B_   2
#define T_   2048
#define C_   1024
#define H_   16
#define HS_  64
#define NROWS 4096
#define C3   3072
#define K1C  0.1803368801111244f    // 0.125 * log2(e), folded into Q

typedef unsigned short ushort_t;
typedef __attribute__((ext_vector_type(8))) short short8;
typedef __attribute__((ext_vector_type(4))) float f32x4;
typedef __attribute__((ext_vector_type(16))) float f32x16;

__device__ __forceinline__ ushort_t f2bf(float f) {
  __hip_bfloat16 h = __float2bfloat16(f);
  ushort_t u; __builtin_memcpy(&u, &h, 2); return u;
}
__device__ __forceinline__ float bf2f(ushort_t u) {
  union { unsigned u; float f; } v; v.u = ((unsigned)u) << 16;
  return v.f;
}
__device__ __forceinline__ unsigned pk2(float a, float b) {
  __hip_bfloat162 t = __float22bfloat162_rn(make_float2(a, b));
  unsigned u; __builtin_memcpy(&u, &t, 4); return u;
}
__device__ __forceinline__ short8 mk8(unsigned a, unsigned b, unsigned c, unsigned d) {
  union { unsigned u[4]; short8 s; } t;
  t.u[0] = a; t.u[1] = b; t.u[2] = c; t.u[3] = d; return t.s;
}
__device__ __forceinline__ void pl32swap(unsigned &a, unsigned &b) {
  asm("v_permlane32_swap_b32 %0, %1" : "+v"(a), "+v"(b));
}
__device__ __forceinline__ f32x4 mfma16(short8 a, short8 b, f32x4 c) {
  return __builtin_amdgcn_mfma_f32_16x16x32_bf16(a, b, c, 0, 0, 0);
}
__device__ __forceinline__ f32x16 mfma32(short8 a, short8 b, f32x16 c) {
  return __builtin_amdgcn_mfma_f32_32x32x16_bf16(a, b, c, 0, 0, 0);
}
typedef const __attribute__((address_space(1))) void g_void;
typedef __attribute__((address_space(3))) void l_void;
__device__ __forceinline__ void gl_lds16(const void* g, void* l) {
  __builtin_amdgcn_global_load_lds((g_void*)g, (l_void*)l, 16, 0, 0);
}

// ---------------- LayerNorm (f32 in -> bf16 out) ----------------
__global__ __launch_bounds__(256) void ln_bf16(
    const float* __restrict__ x, const float* __restrict__ g,
    const float* __restrict__ b, ushort_t* __restrict__ out) {
  int row = blockIdx.x;
  const float* xr = x + (size_t)row * C_;
  int t = threadIdx.x;
  float4 v = ((const float4*)xr)[t];
  float s  = v.x + v.y + v.z + v.w;
  float ss = v.x*v.x + v.y*v.y + v.z*v.z + v.w*v.w;
  #pragma unroll
  for (int off = 32; off > 0; off >>= 1) {
    s  += __shfl_down(s, off);
    ss += __shfl_down(ss, off);
  }
  __shared__ float red[2][4];
  int wid = t >> 6, lane = t & 63;
  if (lane == 0) { red[0][wid] = s; red[1][wid] = ss; }
  __syncthreads();
  if (t == 0) {
    float a = 0, c = 0;
    for (int i = 0; i < 4; i++) { a += red[0][i]; c += red[1][i]; }
    red[0][0] = a; red[1][0] = c;
  }
  __syncthreads();
  float mean = red[0][0] * (1.0f / C_);
  float var  = red[1][0] * (1.0f / C_) - mean * mean;
  float r = rsqrtf(var + 1e-5f);
  float4 gv = ((const float4*)g)[t];
  float4 bv = ((const float4*)b)[t];
  ushort4 o;
  o.x = f2bf((v.x - mean) * r * gv.x + bv.x);
  o.y = f2bf((v.y - mean) * r * gv.y + bv.y);
  o.z = f2bf((v.z - mean) * r * gv.z + bv.z);
  o.w = f2bf((v.w - mean) * r * gv.w + bv.w);
  ((ushort4*)(out + (size_t)row * C_))[t] = o;
}

// ---- merged weight prep ----
__global__ __launch_bounds__(256) void prep_weights(
    const float* __restrict__ Wq, const float* __restrict__ Wk,
    const float* __restrict__ Wv, const float* __restrict__ Wo,
    const float* __restrict__ W1, const float* __restrict__ W2,
    const float* __restrict__ bq, const float* __restrict__ bk,
    const float* __restrict__ bv, ushort_t* __restrict__ Wqkvt,
    ushort_t* __restrict__ Wot3, float* __restrict__ bqkv) {
  int bid = blockIdx.x;
  if (bid < 12288) {
    int idx = bid * 256 + threadIdx.x;
    int n = idx >> 10, c = idx & 1023;
    int sel = n >> 10, nn = n & 1023;
    const float* W = (sel == 0) ? Wq : ((sel == 1) ? Wk : Wv);
    Wqkvt[idx] = f2bf(W[((size_t)(nn >> 6) * C_ + c) * HS_ + (nn & 63)]);
  } else if (bid < 24576) {
    int idx = (bid - 12288) * 256 + threadIdx.x;
    int sel = idx >> 20, rem = idx & 1048575;
    int n = rem >> 10, k = rem & 1023;
    const float* W = (sel == 0) ? Wo : ((sel == 1) ? W1 : W2);
    Wot3[idx] = f2bf(W[(size_t)k * C_ + n]);
  } else {
    int i = (bid - 24576) * 256 + threadIdx.x;
    if (i < 3072)
      bqkv[i] = (i < 1024) ? bq[i] : ((i < 2048) ? bk[i - 1024] : bv[i - 2048]);
  }
}

// ---- unified 128x128 MFMA GEMM: C = A(MxK) * Bt(NxK)^T + bias [opts] ----
template<int OUT_BF16, int RELU, int HAS_RES, int QSCALE>
__global__ __launch_bounds__(256) void gemmT(
    const ushort_t* __restrict__ A, const ushort_t* __restrict__ Bt,
    const float* __restrict__ bias, const float* __restrict__ res,
    void* __restrict__ Cm, int M, int N, int K) {
  __shared__ ushort_t As[128 * 32];
  __shared__ ushort_t Bs[128 * 32];
  int t = threadIdx.x;
  int m0 = blockIdx.y * 128, n0 = blockIdx.x * 128;
  int w = t >> 6, l = t & 63;
  int wr = w >> 1, wc = w & 1;
  int lo = l & 15, hi = l >> 4;
  f32x4 acc[4][4] = {};
  int srow = t >> 2, scol = (t & 3) * 8;
  const ushort_t* Ag = A  + (size_t)(m0 + srow) * K + scol;
  const ushort_t* Bg = Bt + (size_t)(n0 + srow) * K + scol;
  ushort_t* AsP = As + t * 8;
  ushort_t* BsP = Bs + t * 8;
  for (int k0 = 0; k0 < K; k0 += 32) {
    gl_lds16(Ag + k0,          AsP);
    gl_lds16(Ag + 64 * K + k0, AsP + 64 * 32);
    gl_lds16(Bg + k0,          BsP);
    gl_lds16(Bg + 64 * K + k0, BsP + 64 * 32);
    __syncthreads();
    short8 af[4], bfr[4];
    #pragma unroll
    for (int i = 0; i < 4; i++)
      af[i] = *(const short8*)&As[(wr * 64 + i * 16 + lo) * 32 + hi * 8];
    #pragma unroll
    for (int j = 0; j < 4; j++)
      bfr[j] = *(const short8*)&Bs[(wc * 64 + j * 16 + lo) * 32 + hi * 8];
    #pragma unroll
    for (int i = 0; i < 4; i++)
      #pragma unroll
      for (int j = 0; j < 4; j++)
        acc[i][j] = mfma16(af[i], bfr[j], acc[i][j]);
    __syncthreads();
  }
  float qs = QSCALE ? ((n0 < C_) ? K1C : 1.0f) : 1.0f;
  #pragma unroll
  for (int i = 0; i < 4; i++) {
    int m = m0 + wr * 64 + i * 16 + hi * 4;
    #pragma unroll
    for (int j = 0; j < 4; j++) {
      int n = n0 + wc * 64 + j * 16 + lo;
      float bv = bias[n];
      #pragma unroll
      for (int r = 0; r < 4; r++) {
        float v = acc[i][j][r] + bv;
        if (QSCALE) v *= qs;
        if (HAS_RES) v += res[(size_t)(m + r) * N + n];
        if (RELU) v = fmaxf(v, 0.f);
        if (OUT_BF16) ((ushort_t*)Cm)[(size_t)(m + r) * N + n] = f2bf(v);
        else          ((float*)Cm)[(size_t)(m + r) * N + n] = v;
      }
    }
  }
}

// ---- stats: 4 waves x 32 k-rows, Q 3-buffered. XCD-pinned + balanced pairs ----
// bid<256: kb=j (big); bid>=256: kb=15-j (complement). Pair totals 68 iters.
__global__ __launch_bounds__(256) void attn_stats(
    const ushort_t* __restrict__ QKV, float* __restrict__ dinv) {
  int bid = blockIdx.x;
  int xcd = bid & 7, loc = (bid >> 3) & 31, half = bid >> 8;
  int bh = xcd * 4 + (loc & 3);
  int j = loc >> 2;
  int kb = half ? (15 - j) : j;
  int b = bh >> 4, h = bh & 15;
  int t = threadIdx.x, w = t >> 6, l = t & 63, l31 = l & 31, hi32 = l >> 5;
  __shared__ ushort_t Qs[3][32 * 64];
  const ushort_t* Qb = QKV + (size_t)b * T_ * C3 + h * HS_;
  const ushort_t* Kb = Qb + C_;
  int k0w = kb * 128 + w * 32;
  short8 ka[4];
  #pragma unroll
  for (int c = 0; c < 4; c++)
    ka[c] = *(const short8*)(Kb + (size_t)(k0w + l31) * C3 + c * 16 + hi32 * 8);
  float s[16];
  #pragma unroll
  for (int r = 0; r < 16; r++) s[r] = 0.f;

  int sr = t >> 3, slot = t & 7, su = slot ^ (sr & 7);
  const ushort_t* Qsrc = Qb + (size_t)sr * C3 + su * 8;
  int qt0 = kb * 4, cnt = 64 - qt0;
  int dqt = qt0 + w;

  gl_lds16(Qsrc + (size_t)qt0 * 32 * C3, &Qs[0][t * 8]);
  if (cnt > 1) gl_lds16(Qsrc + (size_t)(qt0 + 1) * 32 * C3, &Qs[1][t * 8]);
  for (int i = 0; i < cnt; i++) {
    int qt = qt0 + i;
    int cur = i % 3;
    if (i + 2 < cnt) {
      gl_lds16(Qsrc + (size_t)(qt + 2) * 32 * C3, &Qs[(i + 2) % 3][t * 8]);
      asm volatile("s_waitcnt vmcnt(2)");
    } else if (i + 1 < cnt) {
      asm volatile("s_waitcnt vmcnt(1)");
    } else {
      asm volatile("s_waitcnt vmcnt(0)");
    }
    __builtin_amdgcn_s_barrier();
    __builtin_amdgcn_sched_barrier(0);
    if (qt >= dqt) {
      short8 qf[4];
      #pragma unroll
      for (int c = 0; c < 4; c++)
        qf[c] = *(const short8*)&Qs[cur][l31 * 64 + ((c * 2 + hi32) ^ (l31 & 7)) * 8];
      __builtin_amdgcn_s_setprio(1);
      f32x16 d = {};
      #pragma unroll
      for (int c = 0; c < 4; c++) d = mfma32(ka[c], qf[c], d);
      __builtin_amdgcn_s_setprio(0);
      if (qt == dqt) {
        int qq = qt * 32 + l31;
        #pragma unroll
        for (int r = 0; r < 16; r++) {
          int k = k0w + (r & 3) + 8 * (r >> 2) + 4 * hi32;
          s[r] += (qq >= k) ? exp2f(d[r]) : 0.f;
        }
      } else {
        #pragma unroll
        for (int r = 0; r < 16; r++) s[r] += exp2f(d[r]);
      }
    }
    __builtin_amdgcn_sched_barrier(0);
    __builtin_amdgcn_s_barrier();
    __builtin_amdgcn_sched_barrier(0);
  }
  #pragma unroll
  for (int off = 1; off < 32; off <<= 1)
    #pragma unroll
    for (int r = 0; r < 16; r++)
      s[r] += __shfl_xor(s[r], off);
  if (l31 == 0) {
    #pragma unroll
    for (int r = 0; r < 16; r++) {
      int k = k0w + (r & 3) + 8 * (r >> 2) + 4 * hi32;
      dinv[(size_t)bh * T_ + k] = 1.0f / s[r];
    }
  }
}

// ---- V' = V * dinv, per-head transpose to (bh, HS, T) ----
__global__ __launch_bounds__(256) void transpose_v(
    const ushort_t* __restrict__ QKV, const float* __restrict__ dinv,
    ushort_t* __restrict__ Vt) {
  int t0 = blockIdx.x * 64;
  int bh = blockIdx.y; int b = bh >> 4, h = bh & 15;
  __shared__ ushort_t tile[64][65];
  int tid = threadIdx.x;
  #pragma unroll
  for (int i = 0; i < 16; i++) {
    int idx = i * 256 + tid;
    int tt = idx >> 6, dd = idx & 63;
    float v = bf2f(QKV[(size_t)(b * T_ + t0 + tt) * C3 + 2 * C_ + h * HS_ + dd]);
    tile[tt][dd] = f2bf(v * dinv[(size_t)bh * T_ + t0 + tt]);
  }
  __syncthreads();
  #pragma unroll
  for (int i = 0; i < 16; i++) {
    int idx = i * 256 + tid;
    int dd = idx >> 6, tt = idx & 63;
    Vt[((size_t)(bh * HS_ + dd)) * T_ + t0 + tt] = tile[tt][dd];
  }
}

// ---- PV: 4 waves x 32 q-rows, K/V' 3-buffered. XCD-pinned + balanced pairs ----
// bid<256: qb=15-j (big); bid>=256: qb=j (complement). Pair totals 68 iters.
__global__ __launch_bounds__(256) void attn_pv(
    const ushort_t* __restrict__ QKV, const ushort_t* __restrict__ Vt,
    ushort_t* __restrict__ att) {
  int bid = blockIdx.x;
  int xcd = bid & 7, loc = (bid >> 3) & 31, half = bid >> 8;
  int bh = xcd * 4 + (loc & 3);
  int j = loc >> 2;
  int qb = half ? j : (15 - j);
  int b = bh >> 4, h = bh & 15;
  int t = threadIdx.x, w = t >> 6, l = t & 63, l31 = l & 31, hi32 = l >> 5;
  __shared__ ushort_t Ks[3][32 * 64];
  __shared__ ushort_t Vs[3][32 * 64];
  const ushort_t* Qb = QKV + (size_t)b * T_ * C3 + h * HS_;
  const ushort_t* Kb = Qb + C_;
  const ushort_t* Vb = Vt + (size_t)bh * HS_ * T_;
  int q0w = qb * 128 + w * 32;
  short8 qf[4];
  #pragma unroll
  for (int c = 0; c < 4; c++)
    qf[c] = *(const short8*)(Qb + (size_t)(q0w + l31) * C3 + c * 16 + hi32 * 8);
  f32x16 o0 = {}, o1 = {};
  int nkt = qb * 4 + 4;
  int dkt = q0w >> 5;

  int sr = t >> 3, slot = t & 7, su = slot ^ (sr & 7);
  int vdh = su >> 2, vc2 = su & 3;
  const ushort_t* Ksrc = Kb + (size_t)sr * C3 + su * 8;
  const ushort_t* Vsrc = Vb + (size_t)(vdh * 32 + sr) * T_ + vc2 * 8;

  gl_lds16(Ksrc, &Ks[0][t * 8]);
  gl_lds16(Vsrc, &Vs[0][t * 8]);
  if (nkt > 1) {
    gl_lds16(Ksrc + (size_t)32 * C3, &Ks[1][t * 8]);
    gl_lds16(Vsrc + 32,              &Vs[1][t * 8]);
  }
  for (int kt = 0; kt < nkt; kt++) {
    int cur = kt % 3;
    if (kt + 2 < nkt) {
      gl_lds16(Ksrc + (size_t)(kt + 2) * 32 * C3, &Ks[(kt + 2) % 3][t * 8]);
      gl_lds16(Vsrc + (kt + 2) * 32,              &Vs[(kt + 2) % 3][t * 8]);
      asm volatile("s_waitcnt vmcnt(4)");
    } else if (kt + 1 < nkt) {
      asm volatile("s_waitcnt vmcnt(2)");
    } else {
      asm volatile("s_waitcnt vmcnt(0)");
    }
    __builtin_amdgcn_s_barrier();
    __builtin_amdgcn_sched_barrier(0);
    if (kt <= dkt) {
      short8 ka[4], vf[4];
      #pragma unroll
      for (int c = 0; c < 4; c++)
        ka[c] = *(const short8*)&Ks[cur][l31 * 64 + ((c * 2 + hi32) ^ (l31 & 7)) * 8];
      #pragma unroll
      for (int i = 0; i < 4; i++) {
        int u = (i & 1) * 4 + (i >> 1) * 2 + hi32;
        vf[i] = *(const short8*)&Vs[cur][l31 * 64 + (u ^ (l31 & 7)) * 8];
      }
      __builtin_amdgcn_s_setprio(1);
      f32x16 sacc = {};
      #pragma unroll
      for (int c = 0; c < 4; c++) sacc = mfma32(ka[c], qf[c], sacc);
      __builtin_amdgcn_s_setprio(0);
      float e[16];
      if (kt == dkt) {
        int qq = q0w + l31;
        #pragma unroll
        for (int r = 0; r < 16; r++) {
          int k = kt * 32 + (r & 3) + 8 * (r >> 2) + 4 * hi32;
          e[r] = (k <= qq) ? exp2f(sacc[r]) : 0.f;
        }
      } else {
        #pragma unroll
        for (int r = 0; r < 16; r++) e[r] = exp2f(sacc[r]);
      }
      unsigned u[8];
      #pragma unroll
      for (int j2 = 0; j2 < 8; j2++) u[j2] = pk2(e[2 * j2], e[2 * j2 + 1]);
      pl32swap(u[0], u[2]); pl32swap(u[1], u[3]);
      pl32swap(u[4], u[6]); pl32swap(u[5], u[7]);
      short8 pa0 = mk8(u[0], u[1], u[2], u[3]);
      short8 pa1 = mk8(u[4], u[5], u[6], u[7]);
      __builtin_amdgcn_s_setprio(1);
      o0 = mfma32(pa0, vf[0], o0);
      o1 = mfma32(pa0, vf[1], o1);
      o0 = mfma32(pa1, vf[2], o0);
      o1 = mfma32(pa1, vf[3], o1);
      __builtin_amdgcn_s_setprio(0);
    }
    __builtin_amdgcn_sched_barrier(0);
    __builtin_amdgcn_s_barrier();
    __builtin_amdgcn_sched_barrier(0);
  }

  #pragma unroll
  for (int r = 0; r < 16; r++) {
    int qq = q0w + (r & 3) + 8 * (r >> 2) + 4 * hi32;
    size_t base = (size_t)(b * T_ + qq) * C_ + h * HS_;
    att[base + l31]      = f2bf(o0[r]);
    att[base + 32 + l31] = f2bf(o1[r]);
  }
}

extern "C" void kernel_launch(void* const* d_in, const int* in_sizes, int n_in,
                              void* d_out, int out_size, void* d_ws, size_t ws_size,
                              hipStream_t stream) {
  const float* x   = (const float*)d_in[0];
  const float* Wq  = (const float*)d_in[1];
  const float* bq  = (const float*)d_in[2];
  const float* Wk  = (const float*)d_in[3];
  const float* bk  = (const float*)d_in[4];
  const float* Wv  = (const float*)d_in[5];
  const float* bv  = (const float*)d_in[6];
  const float* Wo  = (const float*)d_in[7];
  const float* bo  = (const float*)d_in[8];
  const float* g1  = (const float*)d_in[9];
  const float* b1  = (const float*)d_in[10];
  const float* g2  = (const float*)d_in[11];
  const float* b2  = (const float*)d_in[12];
  const float* W1  = (const float*)d_in[13];
  const float* bf1 = (const float*)d_in[14];
  const float* W2  = (const float*)d_in[15];
  const float* bf2 = (const float*)d_in[16];
  float* out = (float*)d_out;

  char* base = (char*)d_ws;
  const size_t MB = 1 << 20;
  ushort_t* QKVb  = (ushort_t*)(base);            // 24MB
  ushort_t* hb    = (ushort_t*)(base + 24 * MB);  // 8MB: LN1 out -> att
  ushort_t* Vt    = (ushort_t*)(base + 32 * MB);  // 8MB: V' -> f1b
  float*    y     = (float*)   (base + 40 * MB);  // 16MB
  ushort_t* Wqkvt = (ushort_t*)(base + 56 * MB);  // 6MB
  ushort_t* Wot   = (ushort_t*)(base + 62 * MB);  // 2MB (Wo,W1,W2 contiguous)
  ushort_t* W1t   = (ushort_t*)(base + 64 * MB);
  ushort_t* W2t   = (ushort_t*)(base + 66 * MB);
  float*    bqkv  = (float*)   (base + 68 * MB);  // 12KB
  float*    dinv  = (float*)   (base + 68 * MB + 65536); // 256KB

  prep_weights<<<24588, 256, 0, stream>>>(Wq, Wk, Wv, Wo, W1, W2,
                                          bq, bk, bv, Wqkvt, Wot, bqkv);

  ln_bf16<<<NROWS, 256, 0, stream>>>(x, g1, b1, hb);

  gemmT<1,0,0,1><<<dim3(C3 / 128, NROWS / 128), 256, 0, stream>>>(
      hb, Wqkvt, bqkv, nullptr, QKVb, NROWS, C3, C_);

  attn_stats<<<512, 256, 0, stream>>>(QKVb, dinv);
  transpose_v<<<dim3(T_ / 64, 32), 256, 0, stream>>>(QKVb, dinv, Vt);
  ushort_t* attb = hb;
  attn_pv<<<512, 256, 0, stream>>>(QKVb, Vt, attb);

  dim3 g128(C_ / 128, NROWS / 128);
  gemmT<0,0,1,0><<<g128, 256, 0, stream>>>(attb, Wot, bo, x, y, NROWS, C_, C_);

  ushort_t* h2b = QKVb;
  ln_bf16<<<NROWS, 256, 0, stream>>>(y, g2, b2, h2b);
  ushort_t* f1b = Vt;
  gemmT<1,1,0,0><<<g128, 256, 0, stream>>>(h2b, W1t, bf1, nullptr, f1b, NROWS, C_, C_);
  gemmT<0,0,1,0><<<g128, 256, 0, stream>>>(f1b, W2t, bf2, y, out, NROWS, C_, C_);
}

// Round 14
// 219.790 us; speedup vs baseline: 1.2476x; 1.2396x over previous
//
#include <hip/hip_runtime.h>
#include <hip/hip_bf16.h>
#include <math.h>

// Transformer block B=2 T=2048 C=1024 H=16 HS=64.
// R14: attention VALU diet (2-buffer XOR addressing, precomputed LDS offsets,
// raw v_exp_f32 via builtin, inline-asm v_cvt_pk_bf16_f32) on the R13
// pinned+paired staged structure; 3x N=1024 GEMMs reverted to gemm64
// (512 blocks = 2/CU, R7-proven). Column-softmax (query-axis quirk),
// exp2-only (Q pre-scaled by K1C), dinv folded into V'.

#define B_   2
#define T_   2048
#define C_   1024
#define H_   16
#define HS_  64
#define NROWS 4096
#define C3   3072
#define K1C  0.1803368801111244f    // 0.125 * log2(e), folded into Q

typedef unsigned short ushort_t;
typedef __attribute__((ext_vector_type(8))) short short8;
typedef __attribute__((ext_vector_type(4))) float f32x4;
typedef __attribute__((ext_vector_type(16))) float f32x16;

__device__ __forceinline__ ushort_t f2bf(float f) {
  __hip_bfloat16 h = __float2bfloat16(f);
  ushort_t u; __builtin_memcpy(&u, &h, 2); return u;
}
__device__ __forceinline__ float bf2f(ushort_t u) {
  union { unsigned u; float f; } v; v.u = ((unsigned)u) << 16;
  return v.f;
}
__device__ __forceinline__ unsigned pk2(float a, float b) {
  __hip_bfloat162 t = __float22bfloat162_rn(make_float2(a, b));
  unsigned u; __builtin_memcpy(&u, &t, 4); return u;
}
// hardware packed f32->bf16 pair (lo = cvt(a), hi = cvt(b))
__device__ __forceinline__ unsigned pkhw(float a, float b) {
  unsigned u;
  asm("v_cvt_pk_bf16_f32 %0, %1, %2" : "=v"(u) : "v"(a), "v"(b));
  return u;
}
__device__ __forceinline__ short8 mk8(unsigned a, unsigned b, unsigned c, unsigned d) {
  union { unsigned u[4]; short8 s; } t;
  t.u[0] = a; t.u[1] = b; t.u[2] = c; t.u[3] = d; return t.s;
}
__device__ __forceinline__ void pl32swap(unsigned &a, unsigned &b) {
  asm("v_permlane32_swap_b32 %0, %1" : "+v"(a), "+v"(b));
}
__device__ __forceinline__ f32x4 mfma16(short8 a, short8 b, f32x4 c) {
  return __builtin_amdgcn_mfma_f32_16x16x32_bf16(a, b, c, 0, 0, 0);
}
__device__ __forceinline__ f32x16 mfma32(short8 a, short8 b, f32x16 c) {
  return __builtin_amdgcn_mfma_f32_32x32x16_bf16(a, b, c, 0, 0, 0);
}
typedef const __attribute__((address_space(1))) void g_void;
typedef __attribute__((address_space(3))) void l_void;
__device__ __forceinline__ void gl_lds16(const void* g, void* l) {
  __builtin_amdgcn_global_load_lds((g_void*)g, (l_void*)l, 16, 0, 0);
}

// ---------------- LayerNorm (f32 in -> bf16 out) ----------------
__global__ __launch_bounds__(256) void ln_bf16(
    const float* __restrict__ x, const float* __restrict__ g,
    const float* __restrict__ b, ushort_t* __restrict__ out) {
  int row = blockIdx.x;
  const float* xr = x + (size_t)row * C_;
  int t = threadIdx.x;
  float4 v = ((const float4*)xr)[t];
  float s  = v.x + v.y + v.z + v.w;
  float ss = v.x*v.x + v.y*v.y + v.z*v.z + v.w*v.w;
  #pragma unroll
  for (int off = 32; off > 0; off >>= 1) {
    s  += __shfl_down(s, off);
    ss += __shfl_down(ss, off);
  }
  __shared__ float red[2][4];
  int wid = t >> 6, lane = t & 63;
  if (lane == 0) { red[0][wid] = s; red[1][wid] = ss; }
  __syncthreads();
  if (t == 0) {
    float a = 0, c = 0;
    for (int i = 0; i < 4; i++) { a += red[0][i]; c += red[1][i]; }
    red[0][0] = a; red[1][0] = c;
  }
  __syncthreads();
  float mean = red[0][0] * (1.0f / C_);
  float var  = red[1][0] * (1.0f / C_) - mean * mean;
  float r = rsqrtf(var + 1e-5f);
  float4 gv = ((const float4*)g)[t];
  float4 bv = ((const float4*)b)[t];
  ushort4 o;
  o.x = f2bf((v.x - mean) * r * gv.x + bv.x);
  o.y = f2bf((v.y - mean) * r * gv.y + bv.y);
  o.z = f2bf((v.z - mean) * r * gv.z + bv.z);
  o.w = f2bf((v.w - mean) * r * gv.w + bv.w);
  ((ushort4*)(out + (size_t)row * C_))[t] = o;
}

// ---- merged weight prep ----
__global__ __launch_bounds__(256) void prep_weights(
    const float* __restrict__ Wq, const float* __restrict__ Wk,
    const float* __restrict__ Wv, const float* __restrict__ Wo,
    const float* __restrict__ W1, const float* __restrict__ W2,
    const float* __restrict__ bq, const float* __restrict__ bk,
    const float* __restrict__ bv, ushort_t* __restrict__ Wqkvt,
    ushort_t* __restrict__ Wot3, float* __restrict__ bqkv) {
  int bid = blockIdx.x;
  if (bid < 12288) {
    int idx = bid * 256 + threadIdx.x;
    int n = idx >> 10, c = idx & 1023;
    int sel = n >> 10, nn = n & 1023;
    const float* W = (sel == 0) ? Wq : ((sel == 1) ? Wk : Wv);
    Wqkvt[idx] = f2bf(W[((size_t)(nn >> 6) * C_ + c) * HS_ + (nn & 63)]);
  } else if (bid < 24576) {
    int idx = (bid - 12288) * 256 + threadIdx.x;
    int sel = idx >> 20, rem = idx & 1048575;
    int n = rem >> 10, k = rem & 1023;
    const float* W = (sel == 0) ? Wo : ((sel == 1) ? W1 : W2);
    Wot3[idx] = f2bf(W[(size_t)k * C_ + n]);
  } else {
    int i = (bid - 24576) * 256 + threadIdx.x;
    if (i < 3072)
      bqkv[i] = (i < 1024) ? bq[i] : ((i < 2048) ? bk[i - 1024] : bv[i - 2048]);
  }
}

// ---- 128x128 MFMA GEMM (QKV): C = A * Bt^T + bias, Q third scaled ----
__global__ __launch_bounds__(256) void gemm128q(
    const ushort_t* __restrict__ A, const ushort_t* __restrict__ Bt,
    const float* __restrict__ bias, ushort_t* __restrict__ Cm,
    int M, int N, int K) {
  __shared__ ushort_t As[128 * 32];
  __shared__ ushort_t Bs[128 * 32];
  int t = threadIdx.x;
  int m0 = blockIdx.y * 128, n0 = blockIdx.x * 128;
  int w = t >> 6, l = t & 63;
  int wr = w >> 1, wc = w & 1;
  int lo = l & 15, hi = l >> 4;
  f32x4 acc[4][4] = {};
  int srow = t >> 2, scol = (t & 3) * 8;
  const ushort_t* Ag = A  + (size_t)(m0 + srow) * K + scol;
  const ushort_t* Bg = Bt + (size_t)(n0 + srow) * K + scol;
  ushort_t* AsP = As + t * 8;
  ushort_t* BsP = Bs + t * 8;
  for (int k0 = 0; k0 < K; k0 += 32) {
    gl_lds16(Ag + k0,          AsP);
    gl_lds16(Ag + 64 * K + k0, AsP + 64 * 32);
    gl_lds16(Bg + k0,          BsP);
    gl_lds16(Bg + 64 * K + k0, BsP + 64 * 32);
    __syncthreads();
    short8 af[4], bfr[4];
    #pragma unroll
    for (int i = 0; i < 4; i++)
      af[i] = *(const short8*)&As[(wr * 64 + i * 16 + lo) * 32 + hi * 8];
    #pragma unroll
    for (int j = 0; j < 4; j++)
      bfr[j] = *(const short8*)&Bs[(wc * 64 + j * 16 + lo) * 32 + hi * 8];
    #pragma unroll
    for (int i = 0; i < 4; i++)
      #pragma unroll
      for (int j = 0; j < 4; j++)
        acc[i][j] = mfma16(af[i], bfr[j], acc[i][j]);
    __syncthreads();
  }
  float qs = (n0 < C_) ? K1C : 1.0f;
  #pragma unroll
  for (int i = 0; i < 4; i++) {
    int m = m0 + wr * 64 + i * 16 + hi * 4;
    #pragma unroll
    for (int j = 0; j < 4; j++) {
      int n = n0 + wc * 64 + j * 16 + lo;
      float bv = bias[n];
      #pragma unroll
      for (int r = 0; r < 4; r++)
        Cm[(size_t)(m + r) * N + n] = f2bf((acc[i][j][r] + bv) * qs);
    }
  }
}

// ---------------- GEMM 128x64 tile (N=1024 GEMMs, 512 blocks = 2/CU) ----
template<int OUT_BF16, int RELU, int HAS_RES>
__global__ __launch_bounds__(256) void gemm64(
    const ushort_t* __restrict__ A, const ushort_t* __restrict__ Bt,
    const float* __restrict__ bias, const float* __restrict__ res,
    void* __restrict__ Cm, int M, int N, int K) {
  __shared__ ushort_t As[128 * 32];
  __shared__ ushort_t Bs[64 * 32];
  int t = threadIdx.x;
  int m0 = blockIdx.y * 128, n0 = blockIdx.x * 64;
  int w = t >> 6, l = t & 63;
  int wr = w >> 1, wc = w & 1;
  int lo = l & 15, hi = l >> 4;
  f32x4 acc[4][2] = {};
  int srow = t >> 2, scol = (t & 3) * 8;
  const ushort_t* Ag = A  + (size_t)(m0 + srow) * K + scol;
  const ushort_t* Bg = Bt + (size_t)(n0 + srow) * K + scol;
  ushort_t* AsP = As + t * 8;
  ushort_t* BsP = Bs + t * 8;
  for (int k0 = 0; k0 < K; k0 += 32) {
    gl_lds16(Ag + k0,          AsP);
    gl_lds16(Ag + 64 * K + k0, AsP + 64 * 32);
    gl_lds16(Bg + k0,          BsP);
    __syncthreads();
    short8 af[4], bfr[2];
    #pragma unroll
    for (int i = 0; i < 4; i++)
      af[i] = *(const short8*)&As[(wr * 64 + i * 16 + lo) * 32 + hi * 8];
    #pragma unroll
    for (int j = 0; j < 2; j++)
      bfr[j] = *(const short8*)&Bs[(wc * 32 + j * 16 + lo) * 32 + hi * 8];
    #pragma unroll
    for (int i = 0; i < 4; i++)
      #pragma unroll
      for (int j = 0; j < 2; j++)
        acc[i][j] = mfma16(af[i], bfr[j], acc[i][j]);
    __syncthreads();
  }
  #pragma unroll
  for (int i = 0; i < 4; i++) {
    int m = m0 + wr * 64 + i * 16 + hi * 4;
    #pragma unroll
    for (int j = 0; j < 2; j++) {
      int n = n0 + wc * 32 + j * 16 + lo;
      float bv = bias[n];
      #pragma unroll
      for (int r = 0; r < 4; r++) {
        float v = acc[i][j][r] + bv;
        if (HAS_RES) v += res[(size_t)(m + r) * N + n];
        if (RELU) v = fmaxf(v, 0.f);
        if (OUT_BF16) ((ushort_t*)Cm)[(size_t)(m + r) * N + n] = f2bf(v);
        else          ((float*)Cm)[(size_t)(m + r) * N + n] = v;
      }
    }
  }
}

// ---- stats: 4 waves x 32 k-rows, Q 2-buffered. XCD-pinned + paired ----
__global__ __launch_bounds__(256) void attn_stats(
    const ushort_t* __restrict__ QKV, float* __restrict__ dinv) {
  int bid = blockIdx.x;
  int xcd = bid & 7, loc = (bid >> 3) & 31, half = bid >> 8;
  int bh = xcd * 4 + (loc & 3);
  int j = loc >> 2;
  int kb = half ? (15 - j) : j;
  int b = bh >> 4, h = bh & 15;
  int t = threadIdx.x, w = t >> 6, l = t & 63, l31 = l & 31, hi32 = l >> 5;
  __shared__ ushort_t Qs[2][32 * 64];   // 8KB, 2-buffered
  const ushort_t* Qb = QKV + (size_t)b * T_ * C3 + h * HS_;
  const ushort_t* Kb = Qb + C_;
  int k0w = kb * 128 + w * 32;
  short8 ka[4];
  #pragma unroll
  for (int c = 0; c < 4; c++)
    ka[c] = *(const short8*)(Kb + (size_t)(k0w + l31) * C3 + c * 16 + hi32 * 8);
  float s[16];
  #pragma unroll
  for (int r = 0; r < 16; r++) s[r] = 0.f;

  // precomputed loop-invariant read offsets (elements)
  int qoff[4];
  #pragma unroll
  for (int c = 0; c < 4; c++)
    qoff[c] = l31 * 64 + ((c * 2 + hi32) ^ (l31 & 7)) * 8;
  const ushort_t* Q0 = &Qs[0][0];

  int sr = t >> 3, slot = t & 7, su = slot ^ (sr & 7);
  const ushort_t* Qsrc = Qb + (size_t)sr * C3 + su * 8;
  int qt0 = kb * 4, cnt = 64 - qt0;
  int dqt = qt0 + w;

  gl_lds16(Qsrc + (size_t)qt0 * 32 * C3, &Qs[0][t * 8]);
  for (int i = 0; i < cnt; i++) {
    int qt = qt0 + i, cur = i & 1;
    if (i + 1 < cnt) {
      gl_lds16(Qsrc + (size_t)(qt + 1) * 32 * C3, &Qs[cur ^ 1][t * 8]);
      asm volatile("s_waitcnt vmcnt(1)");
    } else {
      asm volatile("s_waitcnt vmcnt(0)");
    }
    __builtin_amdgcn_s_barrier();
    __builtin_amdgcn_sched_barrier(0);
    if (qt >= dqt) {
      int cb = cur << 11;
      short8 qf[4];
      #pragma unroll
      for (int c = 0; c < 4; c++)
        qf[c] = *(const short8*)(Q0 + cb + qoff[c]);
      __builtin_amdgcn_s_setprio(1);
      f32x16 d = {};
      #pragma unroll
      for (int c = 0; c < 4; c++) d = mfma32(ka[c], qf[c], d);
      __builtin_amdgcn_s_setprio(0);
      if (qt == dqt) {
        int qq = qt * 32 + l31;
        #pragma unroll
        for (int r = 0; r < 16; r++) {
          int k = k0w + (r & 3) + 8 * (r >> 2) + 4 * hi32;
          s[r] += (qq >= k) ? __builtin_amdgcn_exp2f(d[r]) : 0.f;
        }
      } else {
        #pragma unroll
        for (int r = 0; r < 16; r++) s[r] += __builtin_amdgcn_exp2f(d[r]);
      }
    }
    __builtin_amdgcn_sched_barrier(0);
    __builtin_amdgcn_s_barrier();
    __builtin_amdgcn_sched_barrier(0);
  }
  #pragma unroll
  for (int off = 1; off < 32; off <<= 1)
    #pragma unroll
    for (int r = 0; r < 16; r++)
      s[r] += __shfl_xor(s[r], off);
  if (l31 == 0) {
    #pragma unroll
    for (int r = 0; r < 16; r++) {
      int k = k0w + (r & 3) + 8 * (r >> 2) + 4 * hi32;
      dinv[(size_t)bh * T_ + k] = 1.0f / s[r];
    }
  }
}

// ---- V' = V * dinv, per-head transpose to (bh, HS, T) ----
__global__ __launch_bounds__(256) void transpose_v(
    const ushort_t* __restrict__ QKV, const float* __restrict__ dinv,
    ushort_t* __restrict__ Vt) {
  int t0 = blockIdx.x * 64;
  int bh = blockIdx.y; int b = bh >> 4, h = bh & 15;
  __shared__ ushort_t tile[64][65];
  int tid = threadIdx.x;
  #pragma unroll
  for (int i = 0; i < 16; i++) {
    int idx = i * 256 + tid;
    int tt = idx >> 6, dd = idx & 63;
    float v = bf2f(QKV[(size_t)(b * T_ + t0 + tt) * C3 + 2 * C_ + h * HS_ + dd]);
    tile[tt][dd] = f2bf(v * dinv[(size_t)bh * T_ + t0 + tt]);
  }
  __syncthreads();
  #pragma unroll
  for (int i = 0; i < 16; i++) {
    int idx = i * 256 + tid;
    int dd = idx >> 6, tt = idx & 63;
    Vt[((size_t)(bh * HS_ + dd)) * T_ + t0 + tt] = tile[tt][dd];
  }
}

// ---- PV: 4 waves x 32 q-rows, K/V' 2-buffered. XCD-pinned + paired ----
__global__ __launch_bounds__(256) void attn_pv(
    const ushort_t* __restrict__ QKV, const ushort_t* __restrict__ Vt,
    ushort_t* __restrict__ att) {
  int bid = blockIdx.x;
  int xcd = bid & 7, loc = (bid >> 3) & 31, half = bid >> 8;
  int bh = xcd * 4 + (loc & 3);
  int j = loc >> 2;
  int qb = half ? j : (15 - j);
  int b = bh >> 4, h = bh & 15;
  int t = threadIdx.x, w = t >> 6, l = t & 63, l31 = l & 31, hi32 = l >> 5;
  __shared__ ushort_t KV[2][2][32 * 64];   // [buf][K/V], 16KB
  const ushort_t* Qb = QKV + (size_t)b * T_ * C3 + h * HS_;
  const ushort_t* Kb = Qb + C_;
  const ushort_t* Vb = Vt + (size_t)bh * HS_ * T_;
  int q0w = qb * 128 + w * 32;
  short8 qf[4];
  #pragma unroll
  for (int c = 0; c < 4; c++)
    qf[c] = *(const short8*)(Qb + (size_t)(q0w + l31) * C3 + c * 16 + hi32 * 8);
  f32x16 o0 = {}, o1 = {};
  int nkt = qb * 4 + 4;
  int dkt = q0w >> 5;

  // precomputed loop-invariant read offsets (elements, within one buffer)
  int koff[4], voff[4];
  #pragma unroll
  for (int c = 0; c < 4; c++)
    koff[c] = l31 * 64 + ((c * 2 + hi32) ^ (l31 & 7)) * 8;
  #pragma unroll
  for (int i = 0; i < 4; i++) {
    int u = (i & 1) * 4 + (i >> 1) * 2 + hi32;
    voff[i] = 2048 + l31 * 64 + (u ^ (l31 & 7)) * 8;
  }
  const ushort_t* KV0 = &KV[0][0][0];

  int sr = t >> 3, slot = t & 7, su = slot ^ (sr & 7);
  int vdh = su >> 2, vc2 = su & 3;
  const ushort_t* Ksrc = Kb + (size_t)sr * C3 + su * 8;
  const ushort_t* Vsrc = Vb + (size_t)(vdh * 32 + sr) * T_ + vc2 * 8;

  gl_lds16(Ksrc, &KV[0][0][t * 8]);
  gl_lds16(Vsrc, &KV[0][1][t * 8]);
  for (int kt = 0; kt < nkt; kt++) {
    int cur = kt & 1;
    if (kt + 1 < nkt) {
      gl_lds16(Ksrc + (size_t)(kt + 1) * 32 * C3, &KV[cur ^ 1][0][t * 8]);
      gl_lds16(Vsrc + (kt + 1) * 32,              &KV[cur ^ 1][1][t * 8]);
      asm volatile("s_waitcnt vmcnt(2)");
    } else {
      asm volatile("s_waitcnt vmcnt(0)");
    }
    __builtin_amdgcn_s_barrier();
    __builtin_amdgcn_sched_barrier(0);
    if (kt <= dkt) {
      int cb = cur << 12;
      short8 ka[4], vf[4];
      #pragma unroll
      for (int c = 0; c < 4; c++)
        ka[c] = *(const short8*)(KV0 + cb + koff[c]);
      #pragma unroll
      for (int i = 0; i < 4; i++)
        vf[i] = *(const short8*)(KV0 + cb + voff[i]);
      __builtin_amdgcn_s_setprio(1);
      f32x16 sacc = {};
      #pragma unroll
      for (int c = 0; c < 4; c++) sacc = mfma32(ka[c], qf[c], sacc);
      __builtin_amdgcn_s_setprio(0);
      float e[16];
      if (kt == dkt) {
        int qq = q0w + l31;
        #pragma unroll
        for (int r = 0; r < 16; r++) {
          int k = kt * 32 + (r & 3) + 8 * (r >> 2) + 4 * hi32;
          e[r] = (k <= qq) ? __builtin_amdgcn_exp2f(sacc[r]) : 0.f;
        }
      } else {
        #pragma unroll
        for (int r = 0; r < 16; r++) e[r] = __builtin_amdgcn_exp2f(sacc[r]);
      }
      unsigned u[8];
      #pragma unroll
      for (int j2 = 0; j2 < 8; j2++) u[j2] = pkhw(e[2 * j2], e[2 * j2 + 1]);
      pl32swap(u[0], u[2]); pl32swap(u[1], u[3]);
      pl32swap(u[4], u[6]); pl32swap(u[5], u[7]);
      short8 pa0 = mk8(u[0], u[1], u[2], u[3]);
      short8 pa1 = mk8(u[4], u[5], u[6], u[7]);
      __builtin_amdgcn_s_setprio(1);
      o0 = mfma32(pa0, vf[0], o0);
      o1 = mfma32(pa0, vf[1], o1);
      o0 = mfma32(pa1, vf[2], o0);
      o1 = mfma32(pa1, vf[3], o1);
      __builtin_amdgcn_s_setprio(0);
    }
    __builtin_amdgcn_sched_barrier(0);
    __builtin_amdgcn_s_barrier();
    __builtin_amdgcn_sched_barrier(0);
  }

  #pragma unroll
  for (int r = 0; r < 16; r++) {
    int qq = q0w + (r & 3) + 8 * (r >> 2) + 4 * hi32;
    size_t base = (size_t)(b * T_ + qq) * C_ + h * HS_;
    att[base + l31]      = f2bf(o0[r]);
    att[base + 32 + l31] = f2bf(o1[r]);
  }
}

extern "C" void kernel_launch(void* const* d_in, const int* in_sizes, int n_in,
                              void* d_out, int out_size, void* d_ws, size_t ws_size,
                              hipStream_t stream) {
  const float* x   = (const float*)d_in[0];
  const float* Wq  = (const float*)d_in[1];
  const float* bq  = (const float*)d_in[2];
  const float* Wk  = (const float*)d_in[3];
  const float* bk  = (const float*)d_in[4];
  const float* Wv  = (const float*)d_in[5];
  const float* bv  = (const float*)d_in[6];
  const float* Wo  = (const float*)d_in[7];
  const float* bo  = (const float*)d_in[8];
  const float* g1  = (const float*)d_in[9];
  const float* b1  = (const float*)d_in[10];
  const float* g2  = (const float*)d_in[11];
  const float* b2  = (const float*)d_in[12];
  const float* W1  = (const float*)d_in[13];
  const float* bf1 = (const float*)d_in[14];
  const float* W2  = (const float*)d_in[15];
  const float* bf2 = (const float*)d_in[16];
  float* out = (float*)d_out;

  char* base = (char*)d_ws;
  const size_t MB = 1 << 20;
  ushort_t* QKVb  = (ushort_t*)(base);            // 24MB
  ushort_t* hb    = (ushort_t*)(base + 24 * MB);  // 8MB: LN1 out -> att
  ushort_t* Vt    = (ushort_t*)(base + 32 * MB);  // 8MB: V' -> f1b
  float*    y     = (float*)   (base + 40 * MB);  // 16MB
  ushort_t* Wqkvt = (ushort_t*)(base + 56 * MB);  // 6MB
  ushort_t* Wot   = (ushort_t*)(base + 62 * MB);  // 2MB (Wo,W1,W2 contiguous)
  ushort_t* W1t   = (ushort_t*)(base + 64 * MB);
  ushort_t* W2t   = (ushort_t*)(base + 66 * MB);
  float*    bqkv  = (float*)   (base + 68 * MB);  // 12KB
  float*    dinv  = (float*)   (base + 68 * MB + 65536); // 256KB

  prep_weights<<<24588, 256, 0, stream>>>(Wq, Wk, Wv, Wo, W1, W2,
                                          bq, bk, bv, Wqkvt, Wot, bqkv);

  ln_bf16<<<NROWS, 256, 0, stream>>>(x, g1, b1, hb);

  gemm128q<<<dim3(C3 / 128, NROWS / 128), 256, 0, stream>>>(
      hb, Wqkvt, bqkv, QKVb, NROWS, C3, C_);

  attn_stats<<<512, 256, 0, stream>>>(QKVb, dinv);
  transpose_v<<<dim3(T_ / 64, 32), 256, 0, stream>>>(QKVb, dinv, Vt);
  ushort_t* attb = hb;
  attn_pv<<<512, 256, 0, stream>>>(QKVb, Vt, attb);

  dim3 g64(C_ / 64, NROWS / 128);
  gemm64<0,0,1><<<g64, 256, 0, stream>>>(attb, Wot, bo, x, y, NROWS, C_, C_);

  ushort_t* h2b = QKVb;
  ln_bf16<<<NROWS, 256, 0, stream>>>(y, g2, b2, h2b);
  ushort_t* f1b = Vt;
  gemm64<1,1,0><<<g64, 256, 0, stream>>>(h2b, W1t, bf1, nullptr, f1b, NROWS, C_, C_);
  gemm64<0,0,1><<<g64, 256, 0, stream>>>(f1b, W2t, bf2, y, out, NROWS, C_, C_);
}

// Round 15
// 210.418 us; speedup vs baseline: 1.3032x; 1.0445x over previous
//
#include <hip/hip_runtime.h>
#include <hip/hip_bf16.h>
#include <math.h>

// Transformer block B=2 T=2048 C=1024 H=16 HS=64.
// R15: (1) attention pv/stats process 2 tiles per barrier pair (halves the
// per-iter barrier+vmcnt drain that dominated after R14's VALU diet),
// (2) gemm128q gets an XCD-chunked block decode (8mb x 12nb rectangles ->
// ~5MB/XCD working set, cuts 2.5x L2 overfetch). Everything else = R14.
// Column-softmax (query-axis quirk), exp2-only (Q pre-scaled by K1C),
// dinv folded into V'. Math identical to R9-R14 (absmax-verified).

#define B_   2
#define T_   2048
#define C_   1024
#define H_   16
#define HS_  64
#define NROWS 4096
#define C3   3072
#define K1C  0.1803368801111244f    // 0.125 * log2(e), folded into Q

typedef unsigned short ushort_t;
typedef __attribute__((ext_vector_type(8))) short short8;
typedef __attribute__((ext_vector_type(4))) float f32x4;
typedef __attribute__((ext_vector_type(16))) float f32x16;

__device__ __forceinline__ ushort_t f2bf(float f) {
  __hip_bfloat16 h = __float2bfloat16(f);
  ushort_t u; __builtin_memcpy(&u, &h, 2); return u;
}
__device__ __forceinline__ float bf2f(ushort_t u) {
  union { unsigned u; float f; } v; v.u = ((unsigned)u) << 16;
  return v.f;
}
// hardware packed f32->bf16 pair (lo = cvt(a), hi = cvt(b))
__device__ __forceinline__ unsigned pkhw(float a, float b) {
  unsigned u;
  asm("v_cvt_pk_bf16_f32 %0, %1, %2" : "=v"(u) : "v"(a), "v"(b));
  return u;
}
__device__ __forceinline__ short8 mk8(unsigned a, unsigned b, unsigned c, unsigned d) {
  union { unsigned u[4]; short8 s; } t;
  t.u[0] = a; t.u[1] = b; t.u[2] = c; t.u[3] = d; return t.s;
}
__device__ __forceinline__ void pl32swap(unsigned &a, unsigned &b) {
  asm("v_permlane32_swap_b32 %0, %1" : "+v"(a), "+v"(b));
}
__device__ __forceinline__ f32x4 mfma16(short8 a, short8 b, f32x4 c) {
  return __builtin_amdgcn_mfma_f32_16x16x32_bf16(a, b, c, 0, 0, 0);
}
__device__ __forceinline__ f32x16 mfma32(short8 a, short8 b, f32x16 c) {
  return __builtin_amdgcn_mfma_f32_32x32x16_bf16(a, b, c, 0, 0, 0);
}
typedef const __attribute__((address_space(1))) void g_void;
typedef __attribute__((address_space(3))) void l_void;
__device__ __forceinline__ void gl_lds16(const void* g, void* l) {
  __builtin_amdgcn_global_load_lds((g_void*)g, (l_void*)l, 16, 0, 0);
}

// ---------------- LayerNorm (f32 in -> bf16 out) ----------------
__global__ __launch_bounds__(256) void ln_bf16(
    const float* __restrict__ x, const float* __restrict__ g,
    const float* __restrict__ b, ushort_t* __restrict__ out) {
  int row = blockIdx.x;
  const float* xr = x + (size_t)row * C_;
  int t = threadIdx.x;
  float4 v = ((const float4*)xr)[t];
  float s  = v.x + v.y + v.z + v.w;
  float ss = v.x*v.x + v.y*v.y + v.z*v.z + v.w*v.w;
  #pragma unroll
  for (int off = 32; off > 0; off >>= 1) {
    s  += __shfl_down(s, off);
    ss += __shfl_down(ss, off);
  }
  __shared__ float red[2][4];
  int wid = t >> 6, lane = t & 63;
  if (lane == 0) { red[0][wid] = s; red[1][wid] = ss; }
  __syncthreads();
  if (t == 0) {
    float a = 0, c = 0;
    for (int i = 0; i < 4; i++) { a += red[0][i]; c += red[1][i]; }
    red[0][0] = a; red[1][0] = c;
  }
  __syncthreads();
  float mean = red[0][0] * (1.0f / C_);
  float var  = red[1][0] * (1.0f / C_) - mean * mean;
  float r = rsqrtf(var + 1e-5f);
  float4 gv = ((const float4*)g)[t];
  float4 bv = ((const float4*)b)[t];
  ushort4 o;
  o.x = f2bf((v.x - mean) * r * gv.x + bv.x);
  o.y = f2bf((v.y - mean) * r * gv.y + bv.y);
  o.z = f2bf((v.z - mean) * r * gv.z + bv.z);
  o.w = f2bf((v.w - mean) * r * gv.w + bv.w);
  ((ushort4*)(out + (size_t)row * C_))[t] = o;
}

// ---- merged weight prep ----
__global__ __launch_bounds__(256) void prep_weights(
    const float* __restrict__ Wq, const float* __restrict__ Wk,
    const float* __restrict__ Wv, const float* __restrict__ Wo,
    const float* __restrict__ W1, const float* __restrict__ W2,
    const float* __restrict__ bq, const float* __restrict__ bk,
    const float* __restrict__ bv, ushort_t* __restrict__ Wqkvt,
    ushort_t* __restrict__ Wot3, float* __restrict__ bqkv) {
  int bid = blockIdx.x;
  if (bid < 12288) {
    int idx = bid * 256 + threadIdx.x;
    int n = idx >> 10, c = idx & 1023;
    int sel = n >> 10, nn = n & 1023;
    const float* W = (sel == 0) ? Wq : ((sel == 1) ? Wk : Wv);
    Wqkvt[idx] = f2bf(W[((size_t)(nn >> 6) * C_ + c) * HS_ + (nn & 63)]);
  } else if (bid < 24576) {
    int idx = (bid - 12288) * 256 + threadIdx.x;
    int sel = idx >> 20, rem = idx & 1048575;
    int n = rem >> 10, k = rem & 1023;
    const float* W = (sel == 0) ? Wo : ((sel == 1) ? W1 : W2);
    Wot3[idx] = f2bf(W[(size_t)k * C_ + n]);
  } else {
    int i = (bid - 24576) * 256 + threadIdx.x;
    if (i < 3072)
      bqkv[i] = (i < 1024) ? bq[i] : ((i < 2048) ? bk[i - 1024] : bv[i - 2048]);
  }
}

// ---- 128x128 MFMA GEMM (QKV), XCD-chunked decode: 768 blocks -> 8 x (8m x 12n) ----
__global__ __launch_bounds__(256) void gemm128q(
    const ushort_t* __restrict__ A, const ushort_t* __restrict__ Bt,
    const float* __restrict__ bias, ushort_t* __restrict__ Cm,
    int M, int N, int K) {
  __shared__ ushort_t As[128 * 32];
  __shared__ ushort_t Bs[128 * 32];
  int t = threadIdx.x;
  int bid = blockIdx.x;
  int xcd = bid & 7, loc = bid >> 3;        // 0..95
  int mb = (xcd >> 1) * 8 + (loc & 7);      // 0..31
  int nb = (xcd & 1) * 12 + (loc >> 3);     // 0..23
  int m0 = mb * 128, n0 = nb * 128;
  int w = t >> 6, l = t & 63;
  int wr = w >> 1, wc = w & 1;
  int lo = l & 15, hi = l >> 4;
  f32x4 acc[4][4] = {};
  int srow = t >> 2, scol = (t & 3) * 8;
  const ushort_t* Ag = A  + (size_t)(m0 + srow) * K + scol;
  const ushort_t* Bg = Bt + (size_t)(n0 + srow) * K + scol;
  ushort_t* AsP = As + t * 8;
  ushort_t* BsP = Bs + t * 8;
  for (int k0 = 0; k0 < K; k0 += 32) {
    gl_lds16(Ag + k0,          AsP);
    gl_lds16(Ag + 64 * K + k0, AsP + 64 * 32);
    gl_lds16(Bg + k0,          BsP);
    gl_lds16(Bg + 64 * K + k0, BsP + 64 * 32);
    __syncthreads();
    short8 af[4], bfr[4];
    #pragma unroll
    for (int i = 0; i < 4; i++)
      af[i] = *(const short8*)&As[(wr * 64 + i * 16 + lo) * 32 + hi * 8];
    #pragma unroll
    for (int j = 0; j < 4; j++)
      bfr[j] = *(const short8*)&Bs[(wc * 64 + j * 16 + lo) * 32 + hi * 8];
    #pragma unroll
    for (int i = 0; i < 4; i++)
      #pragma unroll
      for (int j = 0; j < 4; j++)
        acc[i][j] = mfma16(af[i], bfr[j], acc[i][j]);
    __syncthreads();
  }
  float qs = (n0 < C_) ? K1C : 1.0f;
  #pragma unroll
  for (int i = 0; i < 4; i++) {
    int m = m0 + wr * 64 + i * 16 + hi * 4;
    #pragma unroll
    for (int j = 0; j < 4; j++) {
      int n = n0 + wc * 64 + j * 16 + lo;
      float bv = bias[n];
      #pragma unroll
      for (int r = 0; r < 4; r++)
        Cm[(size_t)(m + r) * N + n] = f2bf((acc[i][j][r] + bv) * qs);
    }
  }
}

// ---------------- GEMM 128x64 tile (N=1024 GEMMs, 512 blocks = 2/CU) ----
template<int OUT_BF16, int RELU, int HAS_RES>
__global__ __launch_bounds__(256) void gemm64(
    const ushort_t* __restrict__ A, const ushort_t* __restrict__ Bt,
    const float* __restrict__ bias, const float* __restrict__ res,
    void* __restrict__ Cm, int M, int N, int K) {
  __shared__ ushort_t As[128 * 32];
  __shared__ ushort_t Bs[64 * 32];
  int t = threadIdx.x;
  int m0 = blockIdx.y * 128, n0 = blockIdx.x * 64;
  int w = t >> 6, l = t & 63;
  int wr = w >> 1, wc = w & 1;
  int lo = l & 15, hi = l >> 4;
  f32x4 acc[4][2] = {};
  int srow = t >> 2, scol = (t & 3) * 8;
  const ushort_t* Ag = A  + (size_t)(m0 + srow) * K + scol;
  const ushort_t* Bg = Bt + (size_t)(n0 + srow) * K + scol;
  ushort_t* AsP = As + t * 8;
  ushort_t* BsP = Bs + t * 8;
  for (int k0 = 0; k0 < K; k0 += 32) {
    gl_lds16(Ag + k0,          AsP);
    gl_lds16(Ag + 64 * K + k0, AsP + 64 * 32);
    gl_lds16(Bg + k0,          BsP);
    __syncthreads();
    short8 af[4], bfr[2];
    #pragma unroll
    for (int i = 0; i < 4; i++)
      af[i] = *(const short8*)&As[(wr * 64 + i * 16 + lo) * 32 + hi * 8];
    #pragma unroll
    for (int j = 0; j < 2; j++)
      bfr[j] = *(const short8*)&Bs[(wc * 32 + j * 16 + lo) * 32 + hi * 8];
    #pragma unroll
    for (int i = 0; i < 4; i++)
      #pragma unroll
      for (int j = 0; j < 2; j++)
        acc[i][j] = mfma16(af[i], bfr[j], acc[i][j]);
    __syncthreads();
  }
  #pragma unroll
  for (int i = 0; i < 4; i++) {
    int m = m0 + wr * 64 + i * 16 + hi * 4;
    #pragma unroll
    for (int j = 0; j < 2; j++) {
      int n = n0 + wc * 32 + j * 16 + lo;
      float bv = bias[n];
      #pragma unroll
      for (int r = 0; r < 4; r++) {
        float v = acc[i][j][r] + bv;
        if (HAS_RES) v += res[(size_t)(m + r) * N + n];
        if (RELU) v = fmaxf(v, 0.f);
        if (OUT_BF16) ((ushort_t*)Cm)[(size_t)(m + r) * N + n] = f2bf(v);
        else          ((float*)Cm)[(size_t)(m + r) * N + n] = v;
      }
    }
  }
}

// ---- stats: 4 waves x 32 k-rows, TWO Q-tiles per barrier pair ----
__global__ __launch_bounds__(256) void attn_stats(
    const ushort_t* __restrict__ QKV, float* __restrict__ dinv) {
  int bid = blockIdx.x;
  int xcd = bid & 7, loc = (bid >> 3) & 31, half = bid >> 8;
  int bh = xcd * 4 + (loc & 3);
  int j = loc >> 2;
  int kb = half ? (15 - j) : j;
  int b = bh >> 4, h = bh & 15;
  int t = threadIdx.x, w = t >> 6, l = t & 63, l31 = l & 31, hi32 = l >> 5;
  __shared__ ushort_t Qs[2][2][2048];   // [buf][sub] 16KB
  const ushort_t* Qb = QKV + (size_t)b * T_ * C3 + h * HS_;
  const ushort_t* Kb = Qb + C_;
  int k0w = kb * 128 + w * 32;
  short8 ka[4];
  #pragma unroll
  for (int c = 0; c < 4; c++)
    ka[c] = *(const short8*)(Kb + (size_t)(k0w + l31) * C3 + c * 16 + hi32 * 8);
  float s[16];
  #pragma unroll
  for (int r = 0; r < 16; r++) s[r] = 0.f;

  int qoff[4];
  #pragma unroll
  for (int c = 0; c < 4; c++)
    qoff[c] = l31 * 64 + ((c * 2 + hi32) ^ (l31 & 7)) * 8;

  int sr = t >> 3, slot = t & 7, su = slot ^ (sr & 7);
  const ushort_t* Qsrc = Qb + (size_t)sr * C3 + su * 8;
  int qt0 = kb * 4, cnt = 64 - qt0;      // cnt is even
  int dqt = qt0 + w;

  gl_lds16(Qsrc + (size_t)qt0 * 32 * C3,       &Qs[0][0][t * 8]);
  gl_lds16(Qsrc + (size_t)(qt0 + 1) * 32 * C3, &Qs[0][1][t * 8]);
  for (int i = 0; i < cnt; i += 2) {
    int buf = (i >> 1) & 1;
    if (i + 2 < cnt) {
      gl_lds16(Qsrc + (size_t)(qt0 + i + 2) * 32 * C3, &Qs[buf ^ 1][0][t * 8]);
      gl_lds16(Qsrc + (size_t)(qt0 + i + 3) * 32 * C3, &Qs[buf ^ 1][1][t * 8]);
      asm volatile("s_waitcnt vmcnt(2)");
    } else {
      asm volatile("s_waitcnt vmcnt(0)");
    }
    __builtin_amdgcn_s_barrier();
    __builtin_amdgcn_sched_barrier(0);
    #pragma unroll
    for (int sub = 0; sub < 2; sub++) {
      int qt = qt0 + i + sub;
      if (qt >= dqt) {
        const ushort_t* base = &Qs[buf][sub][0];
        short8 qf[4];
        #pragma unroll
        for (int c = 0; c < 4; c++)
          qf[c] = *(const short8*)(base + qoff[c]);
        __builtin_amdgcn_s_setprio(1);
        f32x16 d = {};
        #pragma unroll
        for (int c = 0; c < 4; c++) d = mfma32(ka[c], qf[c], d);
        __builtin_amdgcn_s_setprio(0);
        if (qt == dqt) {
          int qq = qt * 32 + l31;
          #pragma unroll
          for (int r = 0; r < 16; r++) {
            int k = k0w + (r & 3) + 8 * (r >> 2) + 4 * hi32;
            s[r] += (qq >= k) ? __builtin_amdgcn_exp2f(d[r]) : 0.f;
          }
        } else {
          #pragma unroll
          for (int r = 0; r < 16; r++) s[r] += __builtin_amdgcn_exp2f(d[r]);
        }
      }
    }
    __builtin_amdgcn_sched_barrier(0);
    __builtin_amdgcn_s_barrier();
    __builtin_amdgcn_sched_barrier(0);
  }
  #pragma unroll
  for (int off = 1; off < 32; off <<= 1)
    #pragma unroll
    for (int r = 0; r < 16; r++)
      s[r] += __shfl_xor(s[r], off);
  if (l31 == 0) {
    #pragma unroll
    for (int r = 0; r < 16; r++) {
      int k = k0w + (r & 3) + 8 * (r >> 2) + 4 * hi32;
      dinv[(size_t)bh * T_ + k] = 1.0f / s[r];
    }
  }
}

// ---- V' = V * dinv, per-head transpose to (bh, HS, T) ----
__global__ __launch_bounds__(256) void transpose_v(
    const ushort_t* __restrict__ QKV, const float* __restrict__ dinv,
    ushort_t* __restrict__ Vt) {
  int t0 = blockIdx.x * 64;
  int bh = blockIdx.y; int b = bh >> 4, h = bh & 15;
  __shared__ ushort_t tile[64][65];
  int tid = threadIdx.x;
  #pragma unroll
  for (int i = 0; i < 16; i++) {
    int idx = i * 256 + tid;
    int tt = idx >> 6, dd = idx & 63;
    float v = bf2f(QKV[(size_t)(b * T_ + t0 + tt) * C3 + 2 * C_ + h * HS_ + dd]);
    tile[tt][dd] = f2bf(v * dinv[(size_t)bh * T_ + t0 + tt]);
  }
  __syncthreads();
  #pragma unroll
  for (int i = 0; i < 16; i++) {
    int idx = i * 256 + tid;
    int dd = idx >> 6, tt = idx & 63;
    Vt[((size_t)(bh * HS_ + dd)) * T_ + t0 + tt] = tile[tt][dd];
  }
}

// ---- PV: 4 waves x 32 q-rows, TWO k-tiles per barrier pair ----
__global__ __launch_bounds__(256) void attn_pv(
    const ushort_t* __restrict__ QKV, const ushort_t* __restrict__ Vt,
    ushort_t* __restrict__ att) {
  int bid = blockIdx.x;
  int xcd = bid & 7, loc = (bid >> 3) & 31, half = bid >> 8;
  int bh = xcd * 4 + (loc & 3);
  int j = loc >> 2;
  int qb = half ? j : (15 - j);
  int b = bh >> 4, h = bh & 15;
  int t = threadIdx.x, w = t >> 6, l = t & 63, l31 = l & 31, hi32 = l >> 5;
  __shared__ ushort_t KV[2][2][2][2048];   // [buf][sub][K/V] 32KB
  const ushort_t* Qb = QKV + (size_t)b * T_ * C3 + h * HS_;
  const ushort_t* Kb = Qb + C_;
  const ushort_t* Vb = Vt + (size_t)bh * HS_ * T_;
  int q0w = qb * 128 + w * 32;
  short8 qf[4];
  #pragma unroll
  for (int c = 0; c < 4; c++)
    qf[c] = *(const short8*)(Qb + (size_t)(q0w + l31) * C3 + c * 16 + hi32 * 8);
  f32x16 o0 = {}, o1 = {};
  int nkt = qb * 4 + 4;                    // multiple of 4 -> even
  int dkt = q0w >> 5;

  int koff[4], voff[4];
  #pragma unroll
  for (int c = 0; c < 4; c++)
    koff[c] = l31 * 64 + ((c * 2 + hi32) ^ (l31 & 7)) * 8;
  #pragma unroll
  for (int i = 0; i < 4; i++) {
    int u = (i & 1) * 4 + (i >> 1) * 2 + hi32;
    voff[i] = 2048 + l31 * 64 + (u ^ (l31 & 7)) * 8;   // V half at +2048 elems
  }

  int sr = t >> 3, slot = t & 7, su = slot ^ (sr & 7);
  int vdh = su >> 2, vc2 = su & 3;
  const ushort_t* Ksrc = Kb + (size_t)sr * C3 + su * 8;
  const ushort_t* Vsrc = Vb + (size_t)(vdh * 32 + sr) * T_ + vc2 * 8;

  gl_lds16(Ksrc,                  &KV[0][0][0][t * 8]);
  gl_lds16(Vsrc,                  &KV[0][0][1][t * 8]);
  gl_lds16(Ksrc + (size_t)32 * C3, &KV[0][1][0][t * 8]);
  gl_lds16(Vsrc + 32,             &KV[0][1][1][t * 8]);
  for (int kt = 0; kt < nkt; kt += 2) {
    int buf = (kt >> 1) & 1;
    if (kt + 2 < nkt) {
      gl_lds16(Ksrc + (size_t)(kt + 2) * 32 * C3, &KV[buf ^ 1][0][0][t * 8]);
      gl_lds16(Vsrc + (kt + 2) * 32,              &KV[buf ^ 1][0][1][t * 8]);
      gl_lds16(Ksrc + (size_t)(kt + 3) * 32 * C3, &KV[buf ^ 1][1][0][t * 8]);
      gl_lds16(Vsrc + (kt + 3) * 32,              &KV[buf ^ 1][1][1][t * 8]);
      asm volatile("s_waitcnt vmcnt(4)");
    } else {
      asm volatile("s_waitcnt vmcnt(0)");
    }
    __builtin_amdgcn_s_barrier();
    __builtin_amdgcn_sched_barrier(0);
    #pragma unroll
    for (int sub = 0; sub < 2; sub++) {
      int kts = kt + sub;
      if (kts <= dkt) {
        const ushort_t* base = &KV[buf][sub][0][0];
        short8 ka[4], vf[4];
        #pragma unroll
        for (int c = 0; c < 4; c++)
          ka[c] = *(const short8*)(base + koff[c]);
        #pragma unroll
        for (int i = 0; i < 4; i++)
          vf[i] = *(const short8*)(base + voff[i]);
        __builtin_amdgcn_s_setprio(1);
        f32x16 sacc = {};
        #pragma unroll
        for (int c = 0; c < 4; c++) sacc = mfma32(ka[c], qf[c], sacc);
        __builtin_amdgcn_s_setprio(0);
        float e[16];
        if (kts == dkt) {
          int qq = q0w + l31;
          #pragma unroll
          for (int r = 0; r < 16; r++) {
            int k = kts * 32 + (r & 3) + 8 * (r >> 2) + 4 * hi32;
            e[r] = (k <= qq) ? __builtin_amdgcn_exp2f(sacc[r]) : 0.f;
          }
        } else {
          #pragma unroll
          for (int r = 0; r < 16; r++) e[r] = __builtin_amdgcn_exp2f(sacc[r]);
        }
        unsigned u[8];
        #pragma unroll
        for (int j2 = 0; j2 < 8; j2++) u[j2] = pkhw(e[2 * j2], e[2 * j2 + 1]);
        pl32swap(u[0], u[2]); pl32swap(u[1], u[3]);
        pl32swap(u[4], u[6]); pl32swap(u[5], u[7]);
        short8 pa0 = mk8(u[0], u[1], u[2], u[3]);
        short8 pa1 = mk8(u[4], u[5], u[6], u[7]);
        __builtin_amdgcn_s_setprio(1);
        o0 = mfma32(pa0, vf[0], o0);
        o1 = mfma32(pa0, vf[1], o1);
        o0 = mfma32(pa1, vf[2], o0);
        o1 = mfma32(pa1, vf[3], o1);
        __builtin_amdgcn_s_setprio(0);
      }
    }
    __builtin_amdgcn_sched_barrier(0);
    __builtin_amdgcn_s_barrier();
    __builtin_amdgcn_sched_barrier(0);
  }

  #pragma unroll
  for (int r = 0; r < 16; r++) {
    int qq = q0w + (r & 3) + 8 * (r >> 2) + 4 * hi32;
    size_t base = (size_t)(b * T_ + qq) * C_ + h * HS_;
    att[base + l31]      = f2bf(o0[r]);
    att[base + 32 + l31] = f2bf(o1[r]);
  }
}

extern "C" void kernel_launch(void* const* d_in, const int* in_sizes, int n_in,
                              void* d_out, int out_size, void* d_ws, size_t ws_size,
                              hipStream_t stream) {
  const float* x   = (const float*)d_in[0];
  const float* Wq  = (const float*)d_in[1];
  const float* bq  = (const float*)d_in[2];
  const float* Wk  = (const float*)d_in[3];
  const float* bk  = (const float*)d_in[4];
  const float* Wv  = (const float*)d_in[5];
  const float* bv  = (const float*)d_in[6];
  const float* Wo  = (const float*)d_in[7];
  const float* bo  = (const float*)d_in[8];
  const float* g1  = (const float*)d_in[9];
  const float* b1  = (const float*)d_in[10];
  const float* g2  = (const float*)d_in[11];
  const float* b2  = (const float*)d_in[12];
  const float* W1  = (const float*)d_in[13];
  const float* bf1 = (const float*)d_in[14];
  const float* W2  = (const float*)d_in[15];
  const float* bf2 = (const float*)d_in[16];
  float* out = (float*)d_out;

  char* base = (char*)d_ws;
  const size_t MB = 1 << 20;
  ushort_t* QKVb  = (ushort_t*)(base);            // 24MB
  ushort_t* hb    = (ushort_t*)(base + 24 * MB);  // 8MB: LN1 out -> att
  ushort_t* Vt    = (ushort_t*)(base + 32 * MB);  // 8MB: V' -> f1b
  float*    y     = (float*)   (base + 40 * MB);  // 16MB
  ushort_t* Wqkvt = (ushort_t*)(base + 56 * MB);  // 6MB
  ushort_t* Wot   = (ushort_t*)(base + 62 * MB);  // 2MB (Wo,W1,W2 contiguous)
  ushort_t* W1t   = (ushort_t*)(base + 64 * MB);
  ushort_t* W2t   = (ushort_t*)(base + 66 * MB);
  float*    bqkv  = (float*)   (base + 68 * MB);  // 12KB
  float*    dinv  = (float*)   (base + 68 * MB + 65536); // 256KB

  prep_weights<<<24588, 256, 0, stream>>>(Wq, Wk, Wv, Wo, W1, W2,
                                          bq, bk, bv, Wqkvt, Wot, bqkv);

  ln_bf16<<<NROWS, 256, 0, stream>>>(x, g1, b1, hb);

  gemm128q<<<768, 256, 0, stream>>>(hb, Wqkvt, bqkv, QKVb, NROWS, C3, C_);

  attn_stats<<<512, 256, 0, stream>>>(QKVb, dinv);
  transpose_v<<<dim3(T_ / 64, 32), 256, 0, stream>>>(QKVb, dinv, Vt);
  ushort_t* attb = hb;
  attn_pv<<<512, 256, 0, stream>>>(QKVb, Vt, attb);

  dim3 g64(C_ / 64, NROWS / 128);
  gemm64<0,0,1><<<g64, 256, 0, stream>>>(attb, Wot, bo, x, y, NROWS, C_, C_);

  ushort_t* h2b = QKVb;
  ln_bf16<<<NROWS, 256, 0, stream>>>(y, g2, b2, h2b);
  ushort_t* f1b = Vt;
  gemm64<1,1,0><<<g64, 256, 0, stream>>>(h2b, W1t, bf1, nullptr, f1b, NROWS, C_, C_);
  gemm64<0,0,1><<<g64, 256, 0, stream>>>(f1b, W2t, bf2, y, out, NROWS, C_, C_);
}

// Round 16
// 204.364 us; speedup vs baseline: 1.3418x; 1.0296x over previous
//
#include <hip/hip_runtime.h>
#include <hip/hip_bf16.h>
#include <math.h>

// Transformer block B=2 T=2048 C=1024 H=16 HS=64.
// R16: barrier-drain amortization everywhere (R15's proven lever):
//  - GEMMs move BK=32 -> BK=64 (halves barrier pairs 32->16) with T2
//    XOR-slot swizzle (128B rows would otherwise 16-way bank-conflict);
//    pre-swizzled gl_lds16 source + XOR ds_read (same involution as attn).
//  - attention pv/stats batch 4 tiles per barrier pair (was 2), counted
//    vmcnt(8)/(4).
// Column-softmax (query-axis quirk), exp2-only (Q pre-scaled by K1C),
// dinv folded into V'. Math identical to R9-R15 (absmax-verified).

#define B_   2
#define T_   2048
#define C_   1024
#define H_   16
#define HS_  64
#define NROWS 4096
#define C3   3072
#define K1C  0.1803368801111244f    // 0.125 * log2(e), folded into Q

typedef unsigned short ushort_t;
typedef __attribute__((ext_vector_type(8))) short short8;
typedef __attribute__((ext_vector_type(4))) float f32x4;
typedef __attribute__((ext_vector_type(16))) float f32x16;

__device__ __forceinline__ ushort_t f2bf(float f) {
  __hip_bfloat16 h = __float2bfloat16(f);
  ushort_t u; __builtin_memcpy(&u, &h, 2); return u;
}
__device__ __forceinline__ float bf2f(ushort_t u) {
  union { unsigned u; float f; } v; v.u = ((unsigned)u) << 16;
  return v.f;
}
__device__ __forceinline__ unsigned pkhw(float a, float b) {
  unsigned u;
  asm("v_cvt_pk_bf16_f32 %0, %1, %2" : "=v"(u) : "v"(a), "v"(b));
  return u;
}
__device__ __forceinline__ short8 mk8(unsigned a, unsigned b, unsigned c, unsigned d) {
  union { unsigned u[4]; short8 s; } t;
  t.u[0] = a; t.u[1] = b; t.u[2] = c; t.u[3] = d; return t.s;
}
__device__ __forceinline__ void pl32swap(unsigned &a, unsigned &b) {
  asm("v_permlane32_swap_b32 %0, %1" : "+v"(a), "+v"(b));
}
__device__ __forceinline__ f32x4 mfma16(short8 a, short8 b, f32x4 c) {
  return __builtin_amdgcn_mfma_f32_16x16x32_bf16(a, b, c, 0, 0, 0);
}
__device__ __forceinline__ f32x16 mfma32(short8 a, short8 b, f32x16 c) {
  return __builtin_amdgcn_mfma_f32_32x32x16_bf16(a, b, c, 0, 0, 0);
}
typedef const __attribute__((address_space(1))) void g_void;
typedef __attribute__((address_space(3))) void l_void;
__device__ __forceinline__ void gl_lds16(const void* g, void* l) {
  __builtin_amdgcn_global_load_lds((g_void*)g, (l_void*)l, 16, 0, 0);
}

// ---------------- LayerNorm (f32 in -> bf16 out) ----------------
__global__ __launch_bounds__(256) void ln_bf16(
    const float* __restrict__ x, const float* __restrict__ g,
    const float* __restrict__ b, ushort_t* __restrict__ out) {
  int row = blockIdx.x;
  const float* xr = x + (size_t)row * C_;
  int t = threadIdx.x;
  float4 v = ((const float4*)xr)[t];
  float s  = v.x + v.y + v.z + v.w;
  float ss = v.x*v.x + v.y*v.y + v.z*v.z + v.w*v.w;
  #pragma unroll
  for (int off = 32; off > 0; off >>= 1) {
    s  += __shfl_down(s, off);
    ss += __shfl_down(ss, off);
  }
  __shared__ float red[2][4];
  int wid = t >> 6, lane = t & 63;
  if (lane == 0) { red[0][wid] = s; red[1][wid] = ss; }
  __syncthreads();
  if (t == 0) {
    float a = 0, c = 0;
    for (int i = 0; i < 4; i++) { a += red[0][i]; c += red[1][i]; }
    red[0][0] = a; red[1][0] = c;
  }
  __syncthreads();
  float mean = red[0][0] * (1.0f / C_);
  float var  = red[1][0] * (1.0f / C_) - mean * mean;
  float r = rsqrtf(var + 1e-5f);
  float4 gv = ((const float4*)g)[t];
  float4 bv = ((const float4*)b)[t];
  ushort4 o;
  o.x = f2bf((v.x - mean) * r * gv.x + bv.x);
  o.y = f2bf((v.y - mean) * r * gv.y + bv.y);
  o.z = f2bf((v.z - mean) * r * gv.z + bv.z);
  o.w = f2bf((v.w - mean) * r * gv.w + bv.w);
  ((ushort4*)(out + (size_t)row * C_))[t] = o;
}

// ---- merged weight prep ----
__global__ __launch_bounds__(256) void prep_weights(
    const float* __restrict__ Wq, const float* __restrict__ Wk,
    const float* __restrict__ Wv, const float* __restrict__ Wo,
    const float* __restrict__ W1, const float* __restrict__ W2,
    const float* __restrict__ bq, const float* __restrict__ bk,
    const float* __restrict__ bv, ushort_t* __restrict__ Wqkvt,
    ushort_t* __restrict__ Wot3, float* __restrict__ bqkv) {
  int bid = blockIdx.x;
  if (bid < 12288) {
    int idx = bid * 256 + threadIdx.x;
    int n = idx >> 10, c = idx & 1023;
    int sel = n >> 10, nn = n & 1023;
    const float* W = (sel == 0) ? Wq : ((sel == 1) ? Wk : Wv);
    Wqkvt[idx] = f2bf(W[((size_t)(nn >> 6) * C_ + c) * HS_ + (nn & 63)]);
  } else if (bid < 24576) {
    int idx = (bid - 12288) * 256 + threadIdx.x;
    int sel = idx >> 20, rem = idx & 1048575;
    int n = rem >> 10, k = rem & 1023;
    const float* W = (sel == 0) ? Wo : ((sel == 1) ? W1 : W2);
    Wot3[idx] = f2bf(W[(size_t)k * C_ + n]);
  } else {
    int i = (bid - 24576) * 256 + threadIdx.x;
    if (i < 3072)
      bqkv[i] = (i < 1024) ? bq[i] : ((i < 2048) ? bk[i - 1024] : bv[i - 2048]);
  }
}

// ---- QKV GEMM 128x128, BK=64, swizzled LDS, XCD-chunked ----
__global__ __launch_bounds__(256) void gemm128q(
    const ushort_t* __restrict__ A, const ushort_t* __restrict__ Bt,
    const float* __restrict__ bias, ushort_t* __restrict__ Cm,
    int M, int N, int K) {
  __shared__ ushort_t As[128 * 64];   // 16KB, [row][64], XOR-slot swizzled
  __shared__ ushort_t Bs[128 * 64];   // 16KB
  int t = threadIdx.x;
  int bid = blockIdx.x;
  int xcd = bid & 7, loc = bid >> 3;
  int mb = (xcd >> 1) * 8 + (loc & 7);
  int nb = (xcd & 1) * 12 + (loc >> 3);
  int m0 = mb * 128, n0 = nb * 128;
  int w = t >> 6, l = t & 63;
  int wr = w >> 1, wc = w & 1;
  int lo = l & 15, hi = l >> 4;
  f32x4 acc[4][4] = {};
  // staging: row = i*32 + (t>>3), slot = t&7, source slot pre-swizzled
  int srow = t >> 3, ssw = (t & 7) ^ (srow & 7);
  const ushort_t* Ag = A  + (size_t)(m0 + srow) * K + ssw * 8;
  const ushort_t* Bg = Bt + (size_t)(n0 + srow) * K + ssw * 8;
  // read offsets: row*64 + ((kk*4+hi)^(row&7))*8, row&7 == lo&7
  int aoff[4][2], boff[4][2];
  #pragma unroll
  for (int i = 0; i < 4; i++)
    #pragma unroll
    for (int kk = 0; kk < 2; kk++) {
      aoff[i][kk] = (wr * 64 + i * 16 + lo) * 64 + ((kk * 4 + hi) ^ (lo & 7)) * 8;
      boff[i][kk] = (wc * 64 + i * 16 + lo) * 64 + ((kk * 4 + hi) ^ (lo & 7)) * 8;
    }
  for (int k0 = 0; k0 < K; k0 += 64) {
    #pragma unroll
    for (int i = 0; i < 4; i++) {
      gl_lds16(Ag + (size_t)(i * 32) * K + k0, &As[i * 2048 + t * 8]);
      gl_lds16(Bg + (size_t)(i * 32) * K + k0, &Bs[i * 2048 + t * 8]);
    }
    __syncthreads();
    short8 af[4][2], bfr[4][2];
    #pragma unroll
    for (int i = 0; i < 4; i++)
      #pragma unroll
      for (int kk = 0; kk < 2; kk++) {
        af[i][kk]  = *(const short8*)&As[aoff[i][kk]];
        bfr[i][kk] = *(const short8*)&Bs[boff[i][kk]];
      }
    #pragma unroll
    for (int kk = 0; kk < 2; kk++)
      #pragma unroll
      for (int i = 0; i < 4; i++)
        #pragma unroll
        for (int j = 0; j < 4; j++)
          acc[i][j] = mfma16(af[i][kk], bfr[j][kk], acc[i][j]);
    __syncthreads();
  }
  float qs = (n0 < C_) ? K1C : 1.0f;
  #pragma unroll
  for (int i = 0; i < 4; i++) {
    int m = m0 + wr * 64 + i * 16 + hi * 4;
    #pragma unroll
    for (int j = 0; j < 4; j++) {
      int n = n0 + wc * 64 + j * 16 + lo;
      float bv = bias[n];
      #pragma unroll
      for (int r = 0; r < 4; r++)
        Cm[(size_t)(m + r) * N + n] = f2bf((acc[i][j][r] + bv) * qs);
    }
  }
}

// ---- GEMM 128x64, BK=64, swizzled LDS (N=1024 GEMMs, 512 blocks) ----
template<int OUT_BF16, int RELU, int HAS_RES>
__global__ __launch_bounds__(256) void gemm64(
    const ushort_t* __restrict__ A, const ushort_t* __restrict__ Bt,
    const float* __restrict__ bias, const float* __restrict__ res,
    void* __restrict__ Cm, int M, int N, int K) {
  __shared__ ushort_t As[128 * 64];   // 16KB
  __shared__ ushort_t Bs[64 * 64];    // 8KB
  int t = threadIdx.x;
  int m0 = blockIdx.y * 128, n0 = blockIdx.x * 64;
  int w = t >> 6, l = t & 63;
  int wr = w >> 1, wc = w & 1;
  int lo = l & 15, hi = l >> 4;
  f32x4 acc[4][2] = {};
  int srow = t >> 3, ssw = (t & 7) ^ (srow & 7);
  const ushort_t* Ag = A  + (size_t)(m0 + srow) * K + ssw * 8;
  const ushort_t* Bg = Bt + (size_t)(n0 + srow) * K + ssw * 8;
  int aoff[4][2], boff[2][2];
  #pragma unroll
  for (int i = 0; i < 4; i++)
    #pragma unroll
    for (int kk = 0; kk < 2; kk++)
      aoff[i][kk] = (wr * 64 + i * 16 + lo) * 64 + ((kk * 4 + hi) ^ (lo & 7)) * 8;
  #pragma unroll
  for (int j = 0; j < 2; j++)
    #pragma unroll
    for (int kk = 0; kk < 2; kk++)
      boff[j][kk] = (wc * 32 + j * 16 + lo) * 64 + ((kk * 4 + hi) ^ (lo & 7)) * 8;
  for (int k0 = 0; k0 < K; k0 += 64) {
    #pragma unroll
    for (int i = 0; i < 4; i++)
      gl_lds16(Ag + (size_t)(i * 32) * K + k0, &As[i * 2048 + t * 8]);
    #pragma unroll
    for (int i = 0; i < 2; i++)
      gl_lds16(Bg + (size_t)(i * 32) * K + k0, &Bs[i * 2048 + t * 8]);
    __syncthreads();
    short8 af[4][2], bfr[2][2];
    #pragma unroll
    for (int i = 0; i < 4; i++)
      #pragma unroll
      for (int kk = 0; kk < 2; kk++)
        af[i][kk] = *(const short8*)&As[aoff[i][kk]];
    #pragma unroll
    for (int j = 0; j < 2; j++)
      #pragma unroll
      for (int kk = 0; kk < 2; kk++)
        bfr[j][kk] = *(const short8*)&Bs[boff[j][kk]];
    #pragma unroll
    for (int kk = 0; kk < 2; kk++)
      #pragma unroll
      for (int i = 0; i < 4; i++)
        #pragma unroll
        for (int j = 0; j < 2; j++)
          acc[i][j] = mfma16(af[i][kk], bfr[j][kk], acc[i][j]);
    __syncthreads();
  }
  #pragma unroll
  for (int i = 0; i < 4; i++) {
    int m = m0 + wr * 64 + i * 16 + hi * 4;
    #pragma unroll
    for (int j = 0; j < 2; j++) {
      int n = n0 + wc * 32 + j * 16 + lo;
      float bv = bias[n];
      #pragma unroll
      for (int r = 0; r < 4; r++) {
        float v = acc[i][j][r] + bv;
        if (HAS_RES) v += res[(size_t)(m + r) * N + n];
        if (RELU) v = fmaxf(v, 0.f);
        if (OUT_BF16) ((ushort_t*)Cm)[(size_t)(m + r) * N + n] = f2bf(v);
        else          ((float*)Cm)[(size_t)(m + r) * N + n] = v;
      }
    }
  }
}

// ---- stats: 4 waves x 32 k-rows, FOUR Q-tiles per barrier pair ----
__global__ __launch_bounds__(256) void attn_stats(
    const ushort_t* __restrict__ QKV, float* __restrict__ dinv) {
  int bid = blockIdx.x;
  int xcd = bid & 7, loc = (bid >> 3) & 31, half = bid >> 8;
  int bh = xcd * 4 + (loc & 3);
  int j = loc >> 2;
  int kb = half ? (15 - j) : j;
  int b = bh >> 4, h = bh & 15;
  int t = threadIdx.x, w = t >> 6, l = t & 63, l31 = l & 31, hi32 = l >> 5;
  __shared__ ushort_t Qs[2][4][2048];   // 32KB
  const ushort_t* Qb = QKV + (size_t)b * T_ * C3 + h * HS_;
  const ushort_t* Kb = Qb + C_;
  int k0w = kb * 128 + w * 32;
  short8 ka[4];
  #pragma unroll
  for (int c = 0; c < 4; c++)
    ka[c] = *(const short8*)(Kb + (size_t)(k0w + l31) * C3 + c * 16 + hi32 * 8);
  float s[16];
  #pragma unroll
  for (int r = 0; r < 16; r++) s[r] = 0.f;

  int qoff[4];
  #pragma unroll
  for (int c = 0; c < 4; c++)
    qoff[c] = l31 * 64 + ((c * 2 + hi32) ^ (l31 & 7)) * 8;

  int sr = t >> 3, slot = t & 7, su = slot ^ (sr & 7);
  const ushort_t* Qsrc = Qb + (size_t)sr * C3 + su * 8;
  int qt0 = kb * 4, cnt = 64 - qt0;      // multiple of 4
  int dqt = qt0 + w;

  #pragma unroll
  for (int sub = 0; sub < 4; sub++)
    gl_lds16(Qsrc + (size_t)(qt0 + sub) * 32 * C3, &Qs[0][sub][t * 8]);
  for (int i = 0; i < cnt; i += 4) {
    int buf = (i >> 2) & 1;
    if (i + 4 < cnt) {
      #pragma unroll
      for (int sub = 0; sub < 4; sub++)
        gl_lds16(Qsrc + (size_t)(qt0 + i + 4 + sub) * 32 * C3,
                 &Qs[buf ^ 1][sub][t * 8]);
      asm volatile("s_waitcnt vmcnt(4)");
    } else {
      asm volatile("s_waitcnt vmcnt(0)");
    }
    __builtin_amdgcn_s_barrier();
    __builtin_amdgcn_sched_barrier(0);
    #pragma unroll
    for (int sub = 0; sub < 4; sub++) {
      int qt = qt0 + i + sub;
      if (qt >= dqt) {
        const ushort_t* base = &Qs[buf][sub][0];
        short8 qf[4];
        #pragma unroll
        for (int c = 0; c < 4; c++)
          qf[c] = *(const short8*)(base + qoff[c]);
        __builtin_amdgcn_s_setprio(1);
        f32x16 d = {};
        #pragma unroll
        for (int c = 0; c < 4; c++) d = mfma32(ka[c], qf[c], d);
        __builtin_amdgcn_s_setprio(0);
        if (qt == dqt) {
          int qq = qt * 32 + l31;
          #pragma unroll
          for (int r = 0; r < 16; r++) {
            int k = k0w + (r & 3) + 8 * (r >> 2) + 4 * hi32;
            s[r] += (qq >= k) ? __builtin_amdgcn_exp2f(d[r]) : 0.f;
          }
        } else {
          #pragma unroll
          for (int r = 0; r < 16; r++) s[r] += __builtin_amdgcn_exp2f(d[r]);
        }
      }
    }
    __builtin_amdgcn_sched_barrier(0);
    __builtin_amdgcn_s_barrier();
    __builtin_amdgcn_sched_barrier(0);
  }
  #pragma unroll
  for (int off = 1; off < 32; off <<= 1)
    #pragma unroll
    for (int r = 0; r < 16; r++)
      s[r] += __shfl_xor(s[r], off);
  if (l31 == 0) {
    #pragma unroll
    for (int r = 0; r < 16; r++) {
      int k = k0w + (r & 3) + 8 * (r >> 2) + 4 * hi32;
      dinv[(size_t)bh * T_ + k] = 1.0f / s[r];
    }
  }
}

// ---- V' = V * dinv, per-head transpose to (bh, HS, T) ----
__global__ __launch_bounds__(256) void transpose_v(
    const ushort_t* __restrict__ QKV, const float* __restrict__ dinv,
    ushort_t* __restrict__ Vt) {
  int t0 = blockIdx.x * 64;
  int bh = blockIdx.y; int b = bh >> 4, h = bh & 15;
  __shared__ ushort_t tile[64][65];
  int tid = threadIdx.x;
  #pragma unroll
  for (int i = 0; i < 16; i++) {
    int idx = i * 256 + tid;
    int tt = idx >> 6, dd = idx & 63;
    float v = bf2f(QKV[(size_t)(b * T_ + t0 + tt) * C3 + 2 * C_ + h * HS_ + dd]);
    tile[tt][dd] = f2bf(v * dinv[(size_t)bh * T_ + t0 + tt]);
  }
  __syncthreads();
  #pragma unroll
  for (int i = 0; i < 16; i++) {
    int idx = i * 256 + tid;
    int dd = idx >> 6, tt = idx & 63;
    Vt[((size_t)(bh * HS_ + dd)) * T_ + t0 + tt] = tile[tt][dd];
  }
}

// ---- PV: 4 waves x 32 q-rows, FOUR k-tiles per barrier pair ----
__global__ __launch_bounds__(256) void attn_pv(
    const ushort_t* __restrict__ QKV, const ushort_t* __restrict__ Vt,
    ushort_t* __restrict__ att) {
  int bid = blockIdx.x;
  int xcd = bid & 7, loc = (bid >> 3) & 31, half = bid >> 8;
  int bh = xcd * 4 + (loc & 3);
  int j = loc >> 2;
  int qb = half ? j : (15 - j);
  int b = bh >> 4, h = bh & 15;
  int t = threadIdx.x, w = t >> 6, l = t & 63, l31 = l & 31, hi32 = l >> 5;
  __shared__ ushort_t KV[2][4][2][2048];   // [buf][sub][K/V] 64KB
  const ushort_t* Qb = QKV + (size_t)b * T_ * C3 + h * HS_;
  const ushort_t* Kb = Qb + C_;
  const ushort_t* Vb = Vt + (size_t)bh * HS_ * T_;
  int q0w = qb * 128 + w * 32;
  short8 qf[4];
  #pragma unroll
  for (int c = 0; c < 4; c++)
    qf[c] = *(const short8*)(Qb + (size_t)(q0w + l31) * C3 + c * 16 + hi32 * 8);
  f32x16 o0 = {}, o1 = {};
  int nkt = qb * 4 + 4;                    // multiple of 4
  int dkt = q0w >> 5;

  int koff[4], voff[4];
  #pragma unroll
  for (int c = 0; c < 4; c++)
    koff[c] = l31 * 64 + ((c * 2 + hi32) ^ (l31 & 7)) * 8;
  #pragma unroll
  for (int i = 0; i < 4; i++) {
    int u = (i & 1) * 4 + (i >> 1) * 2 + hi32;
    voff[i] = 2048 + l31 * 64 + (u ^ (l31 & 7)) * 8;
  }

  int sr = t >> 3, slot = t & 7, su = slot ^ (sr & 7);
  int vdh = su >> 2, vc2 = su & 3;
  const ushort_t* Ksrc = Kb + (size_t)sr * C3 + su * 8;
  const ushort_t* Vsrc = Vb + (size_t)(vdh * 32 + sr) * T_ + vc2 * 8;

  #pragma unroll
  for (int sub = 0; sub < 4; sub++) {
    gl_lds16(Ksrc + (size_t)sub * 32 * C3, &KV[0][sub][0][t * 8]);
    gl_lds16(Vsrc + sub * 32,              &KV[0][sub][1][t * 8]);
  }
  for (int kt = 0; kt < nkt; kt += 4) {
    int buf = (kt >> 2) & 1;
    if (kt + 4 < nkt) {
      #pragma unroll
      for (int sub = 0; sub < 4; sub++) {
        gl_lds16(Ksrc + (size_t)(kt + 4 + sub) * 32 * C3, &KV[buf ^ 1][sub][0][t * 8]);
        gl_lds16(Vsrc + (kt + 4 + sub) * 32,              &KV[buf ^ 1][sub][1][t * 8]);
      }
      asm volatile("s_waitcnt vmcnt(8)");
    } else {
      asm volatile("s_waitcnt vmcnt(0)");
    }
    __builtin_amdgcn_s_barrier();
    __builtin_amdgcn_sched_barrier(0);
    #pragma unroll
    for (int sub = 0; sub < 4; sub++) {
      int kts = kt + sub;
      if (kts <= dkt) {
        const ushort_t* base = &KV[buf][sub][0][0];
        short8 ka[4], vf[4];
        #pragma unroll
        for (int c = 0; c < 4; c++)
          ka[c] = *(const short8*)(base + koff[c]);
        #pragma unroll
        for (int i = 0; i < 4; i++)
          vf[i] = *(const short8*)(base + voff[i]);
        __builtin_amdgcn_s_setprio(1);
        f32x16 sacc = {};
        #pragma unroll
        for (int c = 0; c < 4; c++) sacc = mfma32(ka[c], qf[c], sacc);
        __builtin_amdgcn_s_setprio(0);
        float e[16];
        if (kts == dkt) {
          int qq = q0w + l31;
          #pragma unroll
          for (int r = 0; r < 16; r++) {
            int k = kts * 32 + (r & 3) + 8 * (r >> 2) + 4 * hi32;
            e[r] = (k <= qq) ? __builtin_amdgcn_exp2f(sacc[r]) : 0.f;
          }
        } else {
          #pragma unroll
          for (int r = 0; r < 16; r++) e[r] = __builtin_amdgcn_exp2f(sacc[r]);
        }
        unsigned u[8];
        #pragma unroll
        for (int j2 = 0; j2 < 8; j2++) u[j2] = pkhw(e[2 * j2], e[2 * j2 + 1]);
        pl32swap(u[0], u[2]); pl32swap(u[1], u[3]);
        pl32swap(u[4], u[6]); pl32swap(u[5], u[7]);
        short8 pa0 = mk8(u[0], u[1], u[2], u[3]);
        short8 pa1 = mk8(u[4], u[5], u[6], u[7]);
        __builtin_amdgcn_s_setprio(1);
        o0 = mfma32(pa0, vf[0], o0);
        o1 = mfma32(pa0, vf[1], o1);
        o0 = mfma32(pa1, vf[2], o0);
        o1 = mfma32(pa1, vf[3], o1);
        __builtin_amdgcn_s_setprio(0);
      }
    }
    __builtin_amdgcn_sched_barrier(0);
    __builtin_amdgcn_s_barrier();
    __builtin_amdgcn_sched_barrier(0);
  }

  #pragma unroll
  for (int r = 0; r < 16; r++) {
    int qq = q0w + (r & 3) + 8 * (r >> 2) + 4 * hi32;
    size_t base = (size_t)(b * T_ + qq) * C_ + h * HS_;
    att[base + l31]      = f2bf(o0[r]);
    att[base + 32 + l31] = f2bf(o1[r]);
  }
}

extern "C" void kernel_launch(void* const* d_in, const int* in_sizes, int n_in,
                              void* d_out, int out_size, void* d_ws, size_t ws_size,
                              hipStream_t stream) {
  const float* x   = (const float*)d_in[0];
  const float* Wq  = (const float*)d_in[1];
  const float* bq  = (const float*)d_in[2];
  const float* Wk  = (const float*)d_in[3];
  const float* bk  = (const float*)d_in[4];
  const float* Wv  = (const float*)d_in[5];
  const float* bv  = (const float*)d_in[6];
  const float* Wo  = (const float*)d_in[7];
  const float* bo  = (const float*)d_in[8];
  const float* g1  = (const float*)d_in[9];
  const float* b1  = (const float*)d_in[10];
  const float* g2  = (const float*)d_in[11];
  const float* b2  = (const float*)d_in[12];
  const float* W1  = (const float*)d_in[13];
  const float* bf1 = (const float*)d_in[14];
  const float* W2  = (const float*)d_in[15];
  const float* bf2 = (const float*)d_in[16];
  float* out = (float*)d_out;

  char* base = (char*)d_ws;
  const size_t MB = 1 << 20;
  ushort_t* QKVb  = (ushort_t*)(base);            // 24MB
  ushort_t* hb    = (ushort_t*)(base + 24 * MB);  // 8MB: LN1 out -> att
  ushort_t* Vt    = (ushort_t*)(base + 32 * MB);  // 8MB: V' -> f1b
  float*    y     = (float*)   (base + 40 * MB);  // 16MB
  ushort_t* Wqkvt = (ushort_t*)(base + 56 * MB);  // 6MB
  ushort_t* Wot   = (ushort_t*)(base + 62 * MB);  // 2MB (Wo,W1,W2 contiguous)
  ushort_t* W1t   = (ushort_t*)(base + 64 * MB);
  ushort_t* W2t   = (ushort_t*)(base + 66 * MB);
  float*    bqkv  = (float*)   (base + 68 * MB);  // 12KB
  float*    dinv  = (float*)   (base + 68 * MB + 65536); // 256KB

  prep_weights<<<24588, 256, 0, stream>>>(Wq, Wk, Wv, Wo, W1, W2,
                                          bq, bk, bv, Wqkvt, Wot, bqkv);

  ln_bf16<<<NROWS, 256, 0, stream>>>(x, g1, b1, hb);

  gemm128q<<<768, 256, 0, stream>>>(hb, Wqkvt, bqkv, QKVb, NROWS, C3, C_);

  attn_stats<<<512, 256, 0, stream>>>(QKVb, dinv);
  transpose_v<<<dim3(T_ / 64, 32), 256, 0, stream>>>(QKVb, dinv, Vt);
  ushort_t* attb = hb;
  attn_pv<<<512, 256, 0, stream>>>(QKVb, Vt, attb);

  dim3 g64(C_ / 64, NROWS / 128);
  gemm64<0,0,1><<<g64, 256, 0, stream>>>(attb, Wot, bo, x, y, NROWS, C_, C_);

  ushort_t* h2b = QKVb;
  ln_bf16<<<NROWS, 256, 0, stream>>>(y, g2, b2, h2b);
  ushort_t* f1b = Vt;
  gemm64<1,1,0><<<g64, 256, 0, stream>>>(h2b, W1t, bf1, nullptr, f1b, NROWS, C_, C_);
  gemm64<0,0,1><<<g64, 256, 0, stream>>>(f1b, W2t, bf2, y, out, NROWS, C_, C_);
}

// Round 17
// 202.469 us; speedup vs baseline: 1.3543x; 1.0094x over previous
//
#include <hip/hip_runtime.h>
#include <hip/hip_bf16.h>
#include <math.h>

// Transformer block B=2 T=2048 C=1024 H=16 HS=64.
// R17: GEMMs get the attention-proven pipeline: BK=32, double-buffered LDS,
// prefetch next K-tile BEFORE compute, counted vmcnt(4)/(3) (never 0
// mid-loop), raw s_barrier + sched_barrier(0), and a 4-slot XOR swizzle
// (s ^= (row>>1)&3) that kills the 3.1M bank-conflict cycles R15 measured.
// Attention kernels identical to R16 (4 tiles per barrier pair).
// Column-softmax (query-axis quirk), exp2-only (Q pre-scaled by K1C),
// dinv folded into V'. Math identical to R9-R16 (absmax-verified).

#define B_   2
#define T_   2048
#define C_   1024
#define H_   16
#define HS_  64
#define NROWS 4096
#define C3   3072
#define K1C  0.1803368801111244f    // 0.125 * log2(e), folded into Q

typedef unsigned short ushort_t;
typedef __attribute__((ext_vector_type(8))) short short8;
typedef __attribute__((ext_vector_type(4))) float f32x4;
typedef __attribute__((ext_vector_type(16))) float f32x16;

__device__ __forceinline__ ushort_t f2bf(float f) {
  __hip_bfloat16 h = __float2bfloat16(f);
  ushort_t u; __builtin_memcpy(&u, &h, 2); return u;
}
__device__ __forceinline__ float bf2f(ushort_t u) {
  union { unsigned u; float f; } v; v.u = ((unsigned)u) << 16;
  return v.f;
}
__device__ __forceinline__ unsigned pkhw(float a, float b) {
  unsigned u;
  asm("v_cvt_pk_bf16_f32 %0, %1, %2" : "=v"(u) : "v"(a), "v"(b));
  return u;
}
__device__ __forceinline__ short8 mk8(unsigned a, unsigned b, unsigned c, unsigned d) {
  union { unsigned u[4]; short8 s; } t;
  t.u[0] = a; t.u[1] = b; t.u[2] = c; t.u[3] = d; return t.s;
}
__device__ __forceinline__ void pl32swap(unsigned &a, unsigned &b) {
  asm("v_permlane32_swap_b32 %0, %1" : "+v"(a), "+v"(b));
}
__device__ __forceinline__ f32x4 mfma16(short8 a, short8 b, f32x4 c) {
  return __builtin_amdgcn_mfma_f32_16x16x32_bf16(a, b, c, 0, 0, 0);
}
__device__ __forceinline__ f32x16 mfma32(short8 a, short8 b, f32x16 c) {
  return __builtin_amdgcn_mfma_f32_32x32x16_bf16(a, b, c, 0, 0, 0);
}
typedef const __attribute__((address_space(1))) void g_void;
typedef __attribute__((address_space(3))) void l_void;
__device__ __forceinline__ void gl_lds16(const void* g, void* l) {
  __builtin_amdgcn_global_load_lds((g_void*)g, (l_void*)l, 16, 0, 0);
}

// ---------------- LayerNorm (f32 in -> bf16 out) ----------------
__global__ __launch_bounds__(256) void ln_bf16(
    const float* __restrict__ x, const float* __restrict__ g,
    const float* __restrict__ b, ushort_t* __restrict__ out) {
  int row = blockIdx.x;
  const float* xr = x + (size_t)row * C_;
  int t = threadIdx.x;
  float4 v = ((const float4*)xr)[t];
  float s  = v.x + v.y + v.z + v.w;
  float ss = v.x*v.x + v.y*v.y + v.z*v.z + v.w*v.w;
  #pragma unroll
  for (int off = 32; off > 0; off >>= 1) {
    s  += __shfl_down(s, off);
    ss += __shfl_down(ss, off);
  }
  __shared__ float red[2][4];
  int wid = t >> 6, lane = t & 63;
  if (lane == 0) { red[0][wid] = s; red[1][wid] = ss; }
  __syncthreads();
  if (t == 0) {
    float a = 0, c = 0;
    for (int i = 0; i < 4; i++) { a += red[0][i]; c += red[1][i]; }
    red[0][0] = a; red[1][0] = c;
  }
  __syncthreads();
  float mean = red[0][0] * (1.0f / C_);
  float var  = red[1][0] * (1.0f / C_) - mean * mean;
  float r = rsqrtf(var + 1e-5f);
  float4 gv = ((const float4*)g)[t];
  float4 bv = ((const float4*)b)[t];
  ushort4 o;
  o.x = f2bf((v.x - mean) * r * gv.x + bv.x);
  o.y = f2bf((v.y - mean) * r * gv.y + bv.y);
  o.z = f2bf((v.z - mean) * r * gv.z + bv.z);
  o.w = f2bf((v.w - mean) * r * gv.w + bv.w);
  ((ushort4*)(out + (size_t)row * C_))[t] = o;
}

// ---- merged weight prep ----
__global__ __launch_bounds__(256) void prep_weights(
    const float* __restrict__ Wq, const float* __restrict__ Wk,
    const float* __restrict__ Wv, const float* __restrict__ Wo,
    const float* __restrict__ W1, const float* __restrict__ W2,
    const float* __restrict__ bq, const float* __restrict__ bk,
    const float* __restrict__ bv, ushort_t* __restrict__ Wqkvt,
    ushort_t* __restrict__ Wot3, float* __restrict__ bqkv) {
  int bid = blockIdx.x;
  if (bid < 12288) {
    int idx = bid * 256 + threadIdx.x;
    int n = idx >> 10, c = idx & 1023;
    int sel = n >> 10, nn = n & 1023;
    const float* W = (sel == 0) ? Wq : ((sel == 1) ? Wk : Wv);
    Wqkvt[idx] = f2bf(W[((size_t)(nn >> 6) * C_ + c) * HS_ + (nn & 63)]);
  } else if (bid < 24576) {
    int idx = (bid - 12288) * 256 + threadIdx.x;
    int sel = idx >> 20, rem = idx & 1048575;
    int n = rem >> 10, k = rem & 1023;
    const float* W = (sel == 0) ? Wo : ((sel == 1) ? W1 : W2);
    Wot3[idx] = f2bf(W[(size_t)k * C_ + n]);
  } else {
    int i = (bid - 24576) * 256 + threadIdx.x;
    if (i < 3072)
      bqkv[i] = (i < 1024) ? bq[i] : ((i < 2048) ? bk[i - 1024] : bv[i - 2048]);
  }
}

// ---- QKV GEMM 128x128, BK=32, DOUBLE-BUFFERED + counted vmcnt, swizzled ----
__global__ __launch_bounds__(256) void gemm128q(
    const ushort_t* __restrict__ A, const ushort_t* __restrict__ Bt,
    const float* __restrict__ bias, ushort_t* __restrict__ Cm,
    int M, int N, int K) {
  __shared__ ushort_t As[2][128 * 32];   // 2 x 8KB
  __shared__ ushort_t Bs[2][128 * 32];   // 2 x 8KB
  int t = threadIdx.x;
  int bid = blockIdx.x;
  int xcd = bid & 7, loc = bid >> 3;
  int mb = (xcd >> 1) * 8 + (loc & 7);
  int nb = (xcd & 1) * 12 + (loc >> 3);
  int m0 = mb * 128, n0 = nb * 128;
  int w = t >> 6, l = t & 63;
  int wr = w >> 1, wc = w & 1;
  int lo = l & 15, hi = l >> 4;
  f32x4 acc[4][4] = {};
  // staging: dest row = t>>2, dest slot = t&3; source slot pre-swizzled
  int srow = t >> 2;
  int sslot = (t & 3) ^ ((srow >> 1) & 3);
  const ushort_t* Ag = A  + (size_t)(m0 + srow) * K + sslot * 8;
  const ushort_t* Bg = Bt + (size_t)(n0 + srow) * K + sslot * 8;
  // read offsets: row*32 + ((hi ^ ((lo>>1)&3)))*8  (row-base multiples of 16)
  int key = (lo >> 1) & 3;
  int aoff[4], boff[4];
  #pragma unroll
  for (int i = 0; i < 4; i++) {
    aoff[i] = (wr * 64 + i * 16 + lo) * 32 + (hi ^ key) * 8;
    boff[i] = (wc * 64 + i * 16 + lo) * 32 + (hi ^ key) * 8;
  }
  int nkt = K >> 5;
  // prologue
  gl_lds16(Ag,          &As[0][t * 8]);
  gl_lds16(Ag + 64 * K, &As[0][64 * 32 + t * 8]);
  gl_lds16(Bg,          &Bs[0][t * 8]);
  gl_lds16(Bg + 64 * K, &Bs[0][64 * 32 + t * 8]);
  for (int kt = 0; kt < nkt; kt++) {
    int cur = kt & 1;
    if (kt + 1 < nkt) {
      int k0 = (kt + 1) * 32;
      gl_lds16(Ag + k0,          &As[cur ^ 1][t * 8]);
      gl_lds16(Ag + 64 * K + k0, &As[cur ^ 1][64 * 32 + t * 8]);
      gl_lds16(Bg + k0,          &Bs[cur ^ 1][t * 8]);
      gl_lds16(Bg + 64 * K + k0, &Bs[cur ^ 1][64 * 32 + t * 8]);
      asm volatile("s_waitcnt vmcnt(4)");
    } else {
      asm volatile("s_waitcnt vmcnt(0)");
    }
    __builtin_amdgcn_s_barrier();
    __builtin_amdgcn_sched_barrier(0);
    short8 af[4], bfr[4];
    #pragma unroll
    for (int i = 0; i < 4; i++) {
      af[i]  = *(const short8*)&As[cur][aoff[i]];
      bfr[i] = *(const short8*)&Bs[cur][boff[i]];
    }
    __builtin_amdgcn_s_setprio(1);
    #pragma unroll
    for (int i = 0; i < 4; i++)
      #pragma unroll
      for (int j = 0; j < 4; j++)
        acc[i][j] = mfma16(af[i], bfr[j], acc[i][j]);
    __builtin_amdgcn_s_setprio(0);
    __builtin_amdgcn_sched_barrier(0);
    __builtin_amdgcn_s_barrier();
    __builtin_amdgcn_sched_barrier(0);
  }
  float qs = (n0 < C_) ? K1C : 1.0f;
  #pragma unroll
  for (int i = 0; i < 4; i++) {
    int m = m0 + wr * 64 + i * 16 + hi * 4;
    #pragma unroll
    for (int j = 0; j < 4; j++) {
      int n = n0 + wc * 64 + j * 16 + lo;
      float bv = bias[n];
      #pragma unroll
      for (int r = 0; r < 4; r++)
        Cm[(size_t)(m + r) * N + n] = f2bf((acc[i][j][r] + bv) * qs);
    }
  }
}

// ---- GEMM 128x64, BK=32, DOUBLE-BUFFERED + counted vmcnt, swizzled ----
template<int OUT_BF16, int RELU, int HAS_RES>
__global__ __launch_bounds__(256) void gemm64(
    const ushort_t* __restrict__ A, const ushort_t* __restrict__ Bt,
    const float* __restrict__ bias, const float* __restrict__ res,
    void* __restrict__ Cm, int M, int N, int K) {
  __shared__ ushort_t As[2][128 * 32];   // 2 x 8KB
  __shared__ ushort_t Bs[2][64 * 32];    // 2 x 4KB
  int t = threadIdx.x;
  int m0 = blockIdx.y * 128, n0 = blockIdx.x * 64;
  int w = t >> 6, l = t & 63;
  int wr = w >> 1, wc = w & 1;
  int lo = l & 15, hi = l >> 4;
  f32x4 acc[4][2] = {};
  int srow = t >> 2;
  int sslot = (t & 3) ^ ((srow >> 1) & 3);
  const ushort_t* Ag = A  + (size_t)(m0 + srow) * K + sslot * 8;
  const ushort_t* Bg = Bt + (size_t)(n0 + srow) * K + sslot * 8;
  int key = (lo >> 1) & 3;
  int aoff[4], boff[2];
  #pragma unroll
  for (int i = 0; i < 4; i++)
    aoff[i] = (wr * 64 + i * 16 + lo) * 32 + (hi ^ key) * 8;
  #pragma unroll
  for (int j = 0; j < 2; j++)
    boff[j] = (wc * 32 + j * 16 + lo) * 32 + (hi ^ key) * 8;
  int nkt = K >> 5;
  gl_lds16(Ag,          &As[0][t * 8]);
  gl_lds16(Ag + 64 * K, &As[0][64 * 32 + t * 8]);
  gl_lds16(Bg,          &Bs[0][t * 8]);
  for (int kt = 0; kt < nkt; kt++) {
    int cur = kt & 1;
    if (kt + 1 < nkt) {
      int k0 = (kt + 1) * 32;
      gl_lds16(Ag + k0,          &As[cur ^ 1][t * 8]);
      gl_lds16(Ag + 64 * K + k0, &As[cur ^ 1][64 * 32 + t * 8]);
      gl_lds16(Bg + k0,          &Bs[cur ^ 1][t * 8]);
      asm volatile("s_waitcnt vmcnt(3)");
    } else {
      asm volatile("s_waitcnt vmcnt(0)");
    }
    __builtin_amdgcn_s_barrier();
    __builtin_amdgcn_sched_barrier(0);
    short8 af[4], bfr[2];
    #pragma unroll
    for (int i = 0; i < 4; i++)
      af[i] = *(const short8*)&As[cur][aoff[i]];
    #pragma unroll
    for (int j = 0; j < 2; j++)
      bfr[j] = *(const short8*)&Bs[cur][boff[j]];
    __builtin_amdgcn_s_setprio(1);
    #pragma unroll
    for (int i = 0; i < 4; i++)
      #pragma unroll
      for (int j = 0; j < 2; j++)
        acc[i][j] = mfma16(af[i], bfr[j], acc[i][j]);
    __builtin_amdgcn_s_setprio(0);
    __builtin_amdgcn_sched_barrier(0);
    __builtin_amdgcn_s_barrier();
    __builtin_amdgcn_sched_barrier(0);
  }
  #pragma unroll
  for (int i = 0; i < 4; i++) {
    int m = m0 + wr * 64 + i * 16 + hi * 4;
    #pragma unroll
    for (int j = 0; j < 2; j++) {
      int n = n0 + wc * 32 + j * 16 + lo;
      float bv = bias[n];
      #pragma unroll
      for (int r = 0; r < 4; r++) {
        float v = acc[i][j][r] + bv;
        if (HAS_RES) v += res[(size_t)(m + r) * N + n];
        if (RELU) v = fmaxf(v, 0.f);
        if (OUT_BF16) ((ushort_t*)Cm)[(size_t)(m + r) * N + n] = f2bf(v);
        else          ((float*)Cm)[(size_t)(m + r) * N + n] = v;
      }
    }
  }
}

// ---- stats: 4 waves x 32 k-rows, FOUR Q-tiles per barrier pair ----
__global__ __launch_bounds__(256) void attn_stats(
    const ushort_t* __restrict__ QKV, float* __restrict__ dinv) {
  int bid = blockIdx.x;
  int xcd = bid & 7, loc = (bid >> 3) & 31, half = bid >> 8;
  int bh = xcd * 4 + (loc & 3);
  int j = loc >> 2;
  int kb = half ? (15 - j) : j;
  int b = bh >> 4, h = bh & 15;
  int t = threadIdx.x, w = t >> 6, l = t & 63, l31 = l & 31, hi32 = l >> 5;
  __shared__ ushort_t Qs[2][4][2048];   // 32KB
  const ushort_t* Qb = QKV + (size_t)b * T_ * C3 + h * HS_;
  const ushort_t* Kb = Qb + C_;
  int k0w = kb * 128 + w * 32;
  short8 ka[4];
  #pragma unroll
  for (int c = 0; c < 4; c++)
    ka[c] = *(const short8*)(Kb + (size_t)(k0w + l31) * C3 + c * 16 + hi32 * 8);
  float s[16];
  #pragma unroll
  for (int r = 0; r < 16; r++) s[r] = 0.f;

  int qoff[4];
  #pragma unroll
  for (int c = 0; c < 4; c++)
    qoff[c] = l31 * 64 + ((c * 2 + hi32) ^ (l31 & 7)) * 8;

  int sr = t >> 3, slot = t & 7, su = slot ^ (sr & 7);
  const ushort_t* Qsrc = Qb + (size_t)sr * C3 + su * 8;
  int qt0 = kb * 4, cnt = 64 - qt0;      // multiple of 4
  int dqt = qt0 + w;

  #pragma unroll
  for (int sub = 0; sub < 4; sub++)
    gl_lds16(Qsrc + (size_t)(qt0 + sub) * 32 * C3, &Qs[0][sub][t * 8]);
  for (int i = 0; i < cnt; i += 4) {
    int buf = (i >> 2) & 1;
    if (i + 4 < cnt) {
      #pragma unroll
      for (int sub = 0; sub < 4; sub++)
        gl_lds16(Qsrc + (size_t)(qt0 + i + 4 + sub) * 32 * C3,
                 &Qs[buf ^ 1][sub][t * 8]);
      asm volatile("s_waitcnt vmcnt(4)");
    } else {
      asm volatile("s_waitcnt vmcnt(0)");
    }
    __builtin_amdgcn_s_barrier();
    __builtin_amdgcn_sched_barrier(0);
    #pragma unroll
    for (int sub = 0; sub < 4; sub++) {
      int qt = qt0 + i + sub;
      if (qt >= dqt) {
        const ushort_t* base = &Qs[buf][sub][0];
        short8 qf[4];
        #pragma unroll
        for (int c = 0; c < 4; c++)
          qf[c] = *(const short8*)(base + qoff[c]);
        __builtin_amdgcn_s_setprio(1);
        f32x16 d = {};
        #pragma unroll
        for (int c = 0; c < 4; c++) d = mfma32(ka[c], qf[c], d);
        __builtin_amdgcn_s_setprio(0);
        if (qt == dqt) {
          int qq = qt * 32 + l31;
          #pragma unroll
          for (int r = 0; r < 16; r++) {
            int k = k0w + (r & 3) + 8 * (r >> 2) + 4 * hi32;
            s[r] += (qq >= k) ? __builtin_amdgcn_exp2f(d[r]) : 0.f;
          }
        } else {
          #pragma unroll
          for (int r = 0; r < 16; r++) s[r] += __builtin_amdgcn_exp2f(d[r]);
        }
      }
    }
    __builtin_amdgcn_sched_barrier(0);
    __builtin_amdgcn_s_barrier();
    __builtin_amdgcn_sched_barrier(0);
  }
  #pragma unroll
  for (int off = 1; off < 32; off <<= 1)
    #pragma unroll
    for (int r = 0; r < 16; r++)
      s[r] += __shfl_xor(s[r], off);
  if (l31 == 0) {
    #pragma unroll
    for (int r = 0; r < 16; r++) {
      int k = k0w + (r & 3) + 8 * (r >> 2) + 4 * hi32;
      dinv[(size_t)bh * T_ + k] = 1.0f / s[r];
    }
  }
}

// ---- V' = V * dinv, per-head transpose to (bh, HS, T) ----
__global__ __launch_bounds__(256) void transpose_v(
    const ushort_t* __restrict__ QKV, const float* __restrict__ dinv,
    ushort_t* __restrict__ Vt) {
  int t0 = blockIdx.x * 64;
  int bh = blockIdx.y; int b = bh >> 4, h = bh & 15;
  __shared__ ushort_t tile[64][65];
  int tid = threadIdx.x;
  #pragma unroll
  for (int i = 0; i < 16; i++) {
    int idx = i * 256 + tid;
    int tt = idx >> 6, dd = idx & 63;
    float v = bf2f(QKV[(size_t)(b * T_ + t0 + tt) * C3 + 2 * C_ + h * HS_ + dd]);
    tile[tt][dd] = f2bf(v * dinv[(size_t)bh * T_ + t0 + tt]);
  }
  __syncthreads();
  #pragma unroll
  for (int i = 0; i < 16; i++) {
    int idx = i * 256 + tid;
    int dd = idx >> 6, tt = idx & 63;
    Vt[((size_t)(bh * HS_ + dd)) * T_ + t0 + tt] = tile[tt][dd];
  }
}

// ---- PV: 4 waves x 32 q-rows, FOUR k-tiles per barrier pair ----
__global__ __launch_bounds__(256) void attn_pv(
    const ushort_t* __restrict__ QKV, const ushort_t* __restrict__ Vt,
    ushort_t* __restrict__ att) {
  int bid = blockIdx.x;
  int xcd = bid & 7, loc = (bid >> 3) & 31, half = bid >> 8;
  int bh = xcd * 4 + (loc & 3);
  int j = loc >> 2;
  int qb = half ? j : (15 - j);
  int b = bh >> 4, h = bh & 15;
  int t = threadIdx.x, w = t >> 6, l = t & 63, l31 = l & 31, hi32 = l >> 5;
  __shared__ ushort_t KV[2][4][2][2048];   // [buf][sub][K/V] 64KB
  const ushort_t* Qb = QKV + (size_t)b * T_ * C3 + h * HS_;
  const ushort_t* Kb = Qb + C_;
  const ushort_t* Vb = Vt + (size_t)bh * HS_ * T_;
  int q0w = qb * 128 + w * 32;
  short8 qf[4];
  #pragma unroll
  for (int c = 0; c < 4; c++)
    qf[c] = *(const short8*)(Qb + (size_t)(q0w + l31) * C3 + c * 16 + hi32 * 8);
  f32x16 o0 = {}, o1 = {};
  int nkt = qb * 4 + 4;                    // multiple of 4
  int dkt = q0w >> 5;

  int koff[4], voff[4];
  #pragma unroll
  for (int c = 0; c < 4; c++)
    koff[c] = l31 * 64 + ((c * 2 + hi32) ^ (l31 & 7)) * 8;
  #pragma unroll
  for (int i = 0; i < 4; i++) {
    int u = (i & 1) * 4 + (i >> 1) * 2 + hi32;
    voff[i] = 2048 + l31 * 64 + (u ^ (l31 & 7)) * 8;
  }

  int sr = t >> 3, slot = t & 7, su = slot ^ (sr & 7);
  int vdh = su >> 2, vc2 = su & 3;
  const ushort_t* Ksrc = Kb + (size_t)sr * C3 + su * 8;
  const ushort_t* Vsrc = Vb + (size_t)(vdh * 32 + sr) * T_ + vc2 * 8;

  #pragma unroll
  for (int sub = 0; sub < 4; sub++) {
    gl_lds16(Ksrc + (size_t)sub * 32 * C3, &KV[0][sub][0][t * 8]);
    gl_lds16(Vsrc + sub * 32,              &KV[0][sub][1][t * 8]);
  }
  for (int kt = 0; kt < nkt; kt += 4) {
    int buf = (kt >> 2) & 1;
    if (kt + 4 < nkt) {
      #pragma unroll
      for (int sub = 0; sub < 4; sub++) {
        gl_lds16(Ksrc + (size_t)(kt + 4 + sub) * 32 * C3, &KV[buf ^ 1][sub][0][t * 8]);
        gl_lds16(Vsrc + (kt + 4 + sub) * 32,              &KV[buf ^ 1][sub][1][t * 8]);
      }
      asm volatile("s_waitcnt vmcnt(8)");
    } else {
      asm volatile("s_waitcnt vmcnt(0)");
    }
    __builtin_amdgcn_s_barrier();
    __builtin_amdgcn_sched_barrier(0);
    #pragma unroll
    for (int sub = 0; sub < 4; sub++) {
      int kts = kt + sub;
      if (kts <= dkt) {
        const ushort_t* base = &KV[buf][sub][0][0];
        short8 ka[4], vf[4];
        #pragma unroll
        for (int c = 0; c < 4; c++)
          ka[c] = *(const short8*)(base + koff[c]);
        #pragma unroll
        for (int i = 0; i < 4; i++)
          vf[i] = *(const short8*)(base + voff[i]);
        __builtin_amdgcn_s_setprio(1);
        f32x16 sacc = {};
        #pragma unroll
        for (int c = 0; c < 4; c++) sacc = mfma32(ka[c], qf[c], sacc);
        __builtin_amdgcn_s_setprio(0);
        float e[16];
        if (kts == dkt) {
          int qq = q0w + l31;
          #pragma unroll
          for (int r = 0; r < 16; r++) {
            int k = kts * 32 + (r & 3) + 8 * (r >> 2) + 4 * hi32;
            e[r] = (k <= qq) ? __builtin_amdgcn_exp2f(sacc[r]) : 0.f;
          }
        } else {
          #pragma unroll
          for (int r = 0; r < 16; r++) e[r] = __builtin_amdgcn_exp2f(sacc[r]);
        }
        unsigned u[8];
        #pragma unroll
        for (int j2 = 0; j2 < 8; j2++) u[j2] = pkhw(e[2 * j2], e[2 * j2 + 1]);
        pl32swap(u[0], u[2]); pl32swap(u[1], u[3]);
        pl32swap(u[4], u[6]); pl32swap(u[5], u[7]);
        short8 pa0 = mk8(u[0], u[1], u[2], u[3]);
        short8 pa1 = mk8(u[4], u[5], u[6], u[7]);
        __builtin_amdgcn_s_setprio(1);
        o0 = mfma32(pa0, vf[0], o0);
        o1 = mfma32(pa0, vf[1], o1);
        o0 = mfma32(pa1, vf[2], o0);
        o1 = mfma32(pa1, vf[3], o1);
        __builtin_amdgcn_s_setprio(0);
      }
    }
    __builtin_amdgcn_sched_barrier(0);
    __builtin_amdgcn_s_barrier();
    __builtin_amdgcn_sched_barrier(0);
  }

  #pragma unroll
  for (int r = 0; r < 16; r++) {
    int qq = q0w + (r & 3) + 8 * (r >> 2) + 4 * hi32;
    size_t base = (size_t)(b * T_ + qq) * C_ + h * HS_;
    att[base + l31]      = f2bf(o0[r]);
    att[base + 32 + l31] = f2bf(o1[r]);
  }
}

extern "C" void kernel_launch(void* const* d_in, const int* in_sizes, int n_in,
                              void* d_out, int out_size, void* d_ws, size_t ws_size,
                              hipStream_t stream) {
  const float* x   = (const float*)d_in[0];
  const float* Wq  = (const float*)d_in[1];
  const float* bq  = (const float*)d_in[2];
  const float* Wk  = (const float*)d_in[3];
  const float* bk  = (const float*)d_in[4];
  const float* Wv  = (const float*)d_in[5];
  const float* bv  = (const float*)d_in[6];
  const float* Wo  = (const float*)d_in[7];
  const float* bo  = (const float*)d_in[8];
  const float* g1  = (const float*)d_in[9];
  const float* b1  = (const float*)d_in[10];
  const float* g2  = (const float*)d_in[11];
  const float* b2  = (const float*)d_in[12];
  const float* W1  = (const float*)d_in[13];
  const float* bf1 = (const float*)d_in[14];
  const float* W2  = (const float*)d_in[15];
  const float* bf2 = (const float*)d_in[16];
  float* out = (float*)d_out;

  char* base = (char*)d_ws;
  const size_t MB = 1 << 20;
  ushort_t* QKVb  = (ushort_t*)(base);            // 24MB
  ushort_t* hb    = (ushort_t*)(base + 24 * MB);  // 8MB: LN1 out -> att
  ushort_t* Vt    = (ushort_t*)(base + 32 * MB);  // 8MB: V' -> f1b
  float*    y     = (float*)   (base + 40 * MB);  // 16MB
  ushort_t* Wqkvt = (ushort_t*)(base + 56 * MB);  // 6MB
  ushort_t* Wot   = (ushort_t*)(base + 62 * MB);  // 2MB (Wo,W1,W2 contiguous)
  ushort_t* W1t   = (ushort_t*)(base + 64 * MB);
  ushort_t* W2t   = (ushort_t*)(base + 66 * MB);
  float*    bqkv  = (float*)   (base + 68 * MB);  // 12KB
  float*    dinv  = (float*)   (base + 68 * MB + 65536); // 256KB

  prep_weights<<<24588, 256, 0, stream>>>(Wq, Wk, Wv, Wo, W1, W2,
                                          bq, bk, bv, Wqkvt, Wot, bqkv);

  ln_bf16<<<NROWS, 256, 0, stream>>>(x, g1, b1, hb);

  gemm128q<<<768, 256, 0, stream>>>(hb, Wqkvt, bqkv, QKVb, NROWS, C3, C_);

  attn_stats<<<512, 256, 0, stream>>>(QKVb, dinv);
  transpose_v<<<dim3(T_ / 64, 32), 256, 0, stream>>>(QKVb, dinv, Vt);
  ushort_t* attb = hb;
  attn_pv<<<512, 256, 0, stream>>>(QKVb, Vt, attb);

  dim3 g64(C_ / 64, NROWS / 128);
  gemm64<0,0,1><<<g64, 256, 0, stream>>>(attb, Wot, bo, x, y, NROWS, C_, C_);

  ushort_t* h2b = QKVb;
  ln_bf16<<<NROWS, 256, 0, stream>>>(y, g2, b2, h2b);
  ushort_t* f1b = Vt;
  gemm64<1,1,0><<<g64, 256, 0, stream>>>(h2b, W1t, bf1, nullptr, f1b, NROWS, C_, C_);
  gemm64<0,0,1><<<g64, 256, 0, stream>>>(f1b, W2t, bf2, y, out, NROWS, C_, C_);
}

// Round 18
// 181.692 us; speedup vs baseline: 1.5092x; 1.1144x over previous
//
#include <hip/hip_runtime.h>
#include <hip/hip_bf16.h>
#include <math.h>

// Transformer block B=2 T=2048 C=1024 H=16 HS=64.
// R18: (1) prep_weights -> LDS-tiled COALESCED transposes (was fully
// uncoalesced: 256B/4KB lane strides, ~25us hidden cost). (2) residual
// stream y -> bf16 (halves its traffic; absmax headroom 4x).
// Attention + GEMMs identical to R17. Column-softmax (query-axis quirk),
// exp2-only (Q pre-scaled by K1C), dinv folded into V'.

#define B_   2
#define T_   2048
#define C_   1024
#define H_   16
#define HS_  64
#define NROWS 4096
#define C3   3072
#define K1C  0.1803368801111244f    // 0.125 * log2(e), folded into Q

typedef unsigned short ushort_t;
typedef __attribute__((ext_vector_type(8))) short short8;
typedef __attribute__((ext_vector_type(4))) float f32x4;
typedef __attribute__((ext_vector_type(16))) float f32x16;

__device__ __forceinline__ ushort_t f2bf(float f) {
  __hip_bfloat16 h = __float2bfloat16(f);
  ushort_t u; __builtin_memcpy(&u, &h, 2); return u;
}
__device__ __forceinline__ float bf2f(ushort_t u) {
  union { unsigned u; float f; } v; v.u = ((unsigned)u) << 16;
  return v.f;
}
__device__ __forceinline__ unsigned pkhw(float a, float b) {
  unsigned u;
  asm("v_cvt_pk_bf16_f32 %0, %1, %2" : "=v"(u) : "v"(a), "v"(b));
  return u;
}
__device__ __forceinline__ short8 mk8(unsigned a, unsigned b, unsigned c, unsigned d) {
  union { unsigned u[4]; short8 s; } t;
  t.u[0] = a; t.u[1] = b; t.u[2] = c; t.u[3] = d; return t.s;
}
__device__ __forceinline__ void pl32swap(unsigned &a, unsigned &b) {
  asm("v_permlane32_swap_b32 %0, %1" : "+v"(a), "+v"(b));
}
__device__ __forceinline__ f32x4 mfma16(short8 a, short8 b, f32x4 c) {
  return __builtin_amdgcn_mfma_f32_16x16x32_bf16(a, b, c, 0, 0, 0);
}
__device__ __forceinline__ f32x16 mfma32(short8 a, short8 b, f32x16 c) {
  return __builtin_amdgcn_mfma_f32_32x32x16_bf16(a, b, c, 0, 0, 0);
}
typedef const __attribute__((address_space(1))) void g_void;
typedef __attribute__((address_space(3))) void l_void;
__device__ __forceinline__ void gl_lds16(const void* g, void* l) {
  __builtin_amdgcn_global_load_lds((g_void*)g, (l_void*)l, 16, 0, 0);
}

// ---------------- LayerNorm (f32 in -> bf16 out) ----------------
__global__ __launch_bounds__(256) void ln_bf16(
    const float* __restrict__ x, const float* __restrict__ g,
    const float* __restrict__ b, ushort_t* __restrict__ out) {
  int row = blockIdx.x;
  const float* xr = x + (size_t)row * C_;
  int t = threadIdx.x;
  float4 v = ((const float4*)xr)[t];
  float s  = v.x + v.y + v.z + v.w;
  float ss = v.x*v.x + v.y*v.y + v.z*v.z + v.w*v.w;
  #pragma unroll
  for (int off = 32; off > 0; off >>= 1) {
    s  += __shfl_down(s, off);
    ss += __shfl_down(ss, off);
  }
  __shared__ float red[2][4];
  int wid = t >> 6, lane = t & 63;
  if (lane == 0) { red[0][wid] = s; red[1][wid] = ss; }
  __syncthreads();
  if (t == 0) {
    float a = 0, c = 0;
    for (int i = 0; i < 4; i++) { a += red[0][i]; c += red[1][i]; }
    red[0][0] = a; red[1][0] = c;
  }
  __syncthreads();
  float mean = red[0][0] * (1.0f / C_);
  float var  = red[1][0] * (1.0f / C_) - mean * mean;
  float r = rsqrtf(var + 1e-5f);
  float4 gv = ((const float4*)g)[t];
  float4 bv = ((const float4*)b)[t];
  ushort4 o;
  o.x = f2bf((v.x - mean) * r * gv.x + bv.x);
  o.y = f2bf((v.y - mean) * r * gv.y + bv.y);
  o.z = f2bf((v.z - mean) * r * gv.z + bv.z);
  o.w = f2bf((v.w - mean) * r * gv.w + bv.w);
  ((ushort4*)(out + (size_t)row * C_))[t] = o;
}

// ---------------- LayerNorm (bf16 in -> bf16 out) ----------------
__global__ __launch_bounds__(256) void ln_bf16_in16(
    const ushort_t* __restrict__ x, const float* __restrict__ g,
    const float* __restrict__ b, ushort_t* __restrict__ out) {
  int row = blockIdx.x;
  const ushort_t* xr = x + (size_t)row * C_;
  int t = threadIdx.x;
  ushort4 uv = ((const ushort4*)xr)[t];
  float v0 = bf2f(uv.x), v1 = bf2f(uv.y), v2 = bf2f(uv.z), v3 = bf2f(uv.w);
  float s  = v0 + v1 + v2 + v3;
  float ss = v0*v0 + v1*v1 + v2*v2 + v3*v3;
  #pragma unroll
  for (int off = 32; off > 0; off >>= 1) {
    s  += __shfl_down(s, off);
    ss += __shfl_down(ss, off);
  }
  __shared__ float red[2][4];
  int wid = t >> 6, lane = t & 63;
  if (lane == 0) { red[0][wid] = s; red[1][wid] = ss; }
  __syncthreads();
  if (t == 0) {
    float a = 0, c = 0;
    for (int i = 0; i < 4; i++) { a += red[0][i]; c += red[1][i]; }
    red[0][0] = a; red[1][0] = c;
  }
  __syncthreads();
  float mean = red[0][0] * (1.0f / C_);
  float var  = red[1][0] * (1.0f / C_) - mean * mean;
  float r = rsqrtf(var + 1e-5f);
  float4 gv = ((const float4*)g)[t];
  float4 bv = ((const float4*)b)[t];
  ushort4 o;
  o.x = f2bf((v0 - mean) * r * gv.x + bv.x);
  o.y = f2bf((v1 - mean) * r * gv.y + bv.y);
  o.z = f2bf((v2 - mean) * r * gv.z + bv.z);
  o.w = f2bf((v3 - mean) * r * gv.w + bv.w);
  ((ushort4*)(out + (size_t)row * C_))[t] = o;
}

// ---- coalesced weight prep: LDS 64x64 tile transposes ----
// bid < 768:  Wqkv (H,C,HS)->(3072,1024): mat=bid/256, h=(bid%256)/16, ct=bid%16
// bid < 1536: Wo/W1/W2 (K,N)->(N,K): mat, nt, kt
// bid == 1536: bias concat
__global__ __launch_bounds__(256) void prep_weights(
    const float* __restrict__ Wq, const float* __restrict__ Wk,
    const float* __restrict__ Wv, const float* __restrict__ Wo,
    const float* __restrict__ W1, const float* __restrict__ W2,
    const float* __restrict__ bq, const float* __restrict__ bk,
    const float* __restrict__ bv, ushort_t* __restrict__ Wqkvt,
    ushort_t* __restrict__ Wot3, float* __restrict__ bqkv) {
  int bid = blockIdx.x;
  int tid = threadIdx.x;
  __shared__ float tile[64][65];
  if (bid < 768) {
    int mat = bid >> 8, rem = bid & 255;
    int h = rem >> 4, ct = rem & 15;
    const float* W = (mat == 0) ? Wq : ((mat == 1) ? Wk : Wv);
    const float* src = W + ((size_t)h * C_ + ct * 64) * HS_;   // rows c, cols d
    #pragma unroll
    for (int i = 0; i < 16; i++) {
      int idx = i * 256 + tid;
      int cc = idx >> 6, dd = idx & 63;
      tile[cc][dd] = src[(size_t)cc * HS_ + dd];               // coalesced in d
    }
    __syncthreads();
    // write Wqkvt[(mat*1024 + h*64 + dd) * 1024 + ct*64 + cc], coalesced in cc
    #pragma unroll
    for (int i = 0; i < 16; i++) {
      int idx = i * 256 + tid;
      int dd = idx >> 6, cc = idx & 63;
      Wqkvt[(size_t)(mat * 1024 + h * 64 + dd) * 1024 + ct * 64 + cc] =
          f2bf(tile[cc][dd]);
    }
  } else if (bid < 1536) {
    int lb = bid - 768;
    int mat = lb >> 8, rem = lb & 255;
    int nt = rem >> 4, kt = rem & 15;
    const float* W = (mat == 0) ? Wo : ((mat == 1) ? W1 : W2);
    const float* src = W + (size_t)(kt * 64) * C_ + nt * 64;   // rows k, cols n
    #pragma unroll
    for (int i = 0; i < 16; i++) {
      int idx = i * 256 + tid;
      int kk = idx >> 6, nn = idx & 63;
      tile[kk][nn] = src[(size_t)kk * C_ + nn];                // coalesced in n
    }
    __syncthreads();
    // write Wot3[mat*1M + (nt*64+nn)*1024 + kt*64 + kk], coalesced in kk
    #pragma unroll
    for (int i = 0; i < 16; i++) {
      int idx = i * 256 + tid;
      int nn = idx >> 6, kk = idx & 63;
      Wot3[(size_t)mat * 1048576 + (size_t)(nt * 64 + nn) * 1024 + kt * 64 + kk] =
          f2bf(tile[kk][nn]);
    }
  } else {
    for (int i = tid; i < 3072; i += 256)
      bqkv[i] = (i < 1024) ? bq[i] : ((i < 2048) ? bk[i - 1024] : bv[i - 2048]);
  }
}

// ---- QKV GEMM 128x128, BK=32, double-buffered + counted vmcnt, swizzled ----
__global__ __launch_bounds__(256) void gemm128q(
    const ushort_t* __restrict__ A, const ushort_t* __restrict__ Bt,
    const float* __restrict__ bias, ushort_t* __restrict__ Cm,
    int M, int N, int K) {
  __shared__ ushort_t As[2][128 * 32];
  __shared__ ushort_t Bs[2][128 * 32];
  int t = threadIdx.x;
  int bid = blockIdx.x;
  int xcd = bid & 7, loc = bid >> 3;
  int mb = (xcd >> 1) * 8 + (loc & 7);
  int nb = (xcd & 1) * 12 + (loc >> 3);
  int m0 = mb * 128, n0 = nb * 128;
  int w = t >> 6, l = t & 63;
  int wr = w >> 1, wc = w & 1;
  int lo = l & 15, hi = l >> 4;
  f32x4 acc[4][4] = {};
  int srow = t >> 2;
  int sslot = (t & 3) ^ ((srow >> 1) & 3);
  const ushort_t* Ag = A  + (size_t)(m0 + srow) * K + sslot * 8;
  const ushort_t* Bg = Bt + (size_t)(n0 + srow) * K + sslot * 8;
  int key = (lo >> 1) & 3;
  int aoff[4], boff[4];
  #pragma unroll
  for (int i = 0; i < 4; i++) {
    aoff[i] = (wr * 64 + i * 16 + lo) * 32 + (hi ^ key) * 8;
    boff[i] = (wc * 64 + i * 16 + lo) * 32 + (hi ^ key) * 8;
  }
  int nkt = K >> 5;
  gl_lds16(Ag,          &As[0][t * 8]);
  gl_lds16(Ag + 64 * K, &As[0][64 * 32 + t * 8]);
  gl_lds16(Bg,          &Bs[0][t * 8]);
  gl_lds16(Bg + 64 * K, &Bs[0][64 * 32 + t * 8]);
  for (int kt = 0; kt < nkt; kt++) {
    int cur = kt & 1;
    if (kt + 1 < nkt) {
      int k0 = (kt + 1) * 32;
      gl_lds16(Ag + k0,          &As[cur ^ 1][t * 8]);
      gl_lds16(Ag + 64 * K + k0, &As[cur ^ 1][64 * 32 + t * 8]);
      gl_lds16(Bg + k0,          &Bs[cur ^ 1][t * 8]);
      gl_lds16(Bg + 64 * K + k0, &Bs[cur ^ 1][64 * 32 + t * 8]);
      asm volatile("s_waitcnt vmcnt(4)");
    } else {
      asm volatile("s_waitcnt vmcnt(0)");
    }
    __builtin_amdgcn_s_barrier();
    __builtin_amdgcn_sched_barrier(0);
    short8 af[4], bfr[4];
    #pragma unroll
    for (int i = 0; i < 4; i++) {
      af[i]  = *(const short8*)&As[cur][aoff[i]];
      bfr[i] = *(const short8*)&Bs[cur][boff[i]];
    }
    __builtin_amdgcn_s_setprio(1);
    #pragma unroll
    for (int i = 0; i < 4; i++)
      #pragma unroll
      for (int j = 0; j < 4; j++)
        acc[i][j] = mfma16(af[i], bfr[j], acc[i][j]);
    __builtin_amdgcn_s_setprio(0);
    __builtin_amdgcn_sched_barrier(0);
    __builtin_amdgcn_s_barrier();
    __builtin_amdgcn_sched_barrier(0);
  }
  float qs = (n0 < C_) ? K1C : 1.0f;
  #pragma unroll
  for (int i = 0; i < 4; i++) {
    int m = m0 + wr * 64 + i * 16 + hi * 4;
    #pragma unroll
    for (int j = 0; j < 4; j++) {
      int n = n0 + wc * 64 + j * 16 + lo;
      float bv = bias[n];
      #pragma unroll
      for (int r = 0; r < 4; r++)
        Cm[(size_t)(m + r) * N + n] = f2bf((acc[i][j][r] + bv) * qs);
    }
  }
}

// ---- GEMM 128x64, BK=32, double-buffered + counted vmcnt, swizzled ----
// RES_BF16: residual pointer is bf16 (otherwise f32)
template<int OUT_BF16, int RELU, int HAS_RES, int RES_BF16>
__global__ __launch_bounds__(256) void gemm64(
    const ushort_t* __restrict__ A, const ushort_t* __restrict__ Bt,
    const float* __restrict__ bias, const void* __restrict__ res,
    void* __restrict__ Cm, int M, int N, int K) {
  __shared__ ushort_t As[2][128 * 32];
  __shared__ ushort_t Bs[2][64 * 32];
  int t = threadIdx.x;
  int m0 = blockIdx.y * 128, n0 = blockIdx.x * 64;
  int w = t >> 6, l = t & 63;
  int wr = w >> 1, wc = w & 1;
  int lo = l & 15, hi = l >> 4;
  f32x4 acc[4][2] = {};
  int srow = t >> 2;
  int sslot = (t & 3) ^ ((srow >> 1) & 3);
  const ushort_t* Ag = A  + (size_t)(m0 + srow) * K + sslot * 8;
  const ushort_t* Bg = Bt + (size_t)(n0 + srow) * K + sslot * 8;
  int key = (lo >> 1) & 3;
  int aoff[4], boff[2];
  #pragma unroll
  for (int i = 0; i < 4; i++)
    aoff[i] = (wr * 64 + i * 16 + lo) * 32 + (hi ^ key) * 8;
  #pragma unroll
  for (int j = 0; j < 2; j++)
    boff[j] = (wc * 32 + j * 16 + lo) * 32 + (hi ^ key) * 8;
  int nkt = K >> 5;
  gl_lds16(Ag,          &As[0][t * 8]);
  gl_lds16(Ag + 64 * K, &As[0][64 * 32 + t * 8]);
  gl_lds16(Bg,          &Bs[0][t * 8]);
  for (int kt = 0; kt < nkt; kt++) {
    int cur = kt & 1;
    if (kt + 1 < nkt) {
      int k0 = (kt + 1) * 32;
      gl_lds16(Ag + k0,          &As[cur ^ 1][t * 8]);
      gl_lds16(Ag + 64 * K + k0, &As[cur ^ 1][64 * 32 + t * 8]);
      gl_lds16(Bg + k0,          &Bs[cur ^ 1][t * 8]);
      asm volatile("s_waitcnt vmcnt(3)");
    } else {
      asm volatile("s_waitcnt vmcnt(0)");
    }
    __builtin_amdgcn_s_barrier();
    __builtin_amdgcn_sched_barrier(0);
    short8 af[4], bfr[2];
    #pragma unroll
    for (int i = 0; i < 4; i++)
      af[i] = *(const short8*)&As[cur][aoff[i]];
    #pragma unroll
    for (int j = 0; j < 2; j++)
      bfr[j] = *(const short8*)&Bs[cur][boff[j]];
    __builtin_amdgcn_s_setprio(1);
    #pragma unroll
    for (int i = 0; i < 4; i++)
      #pragma unroll
      for (int j = 0; j < 2; j++)
        acc[i][j] = mfma16(af[i], bfr[j], acc[i][j]);
    __builtin_amdgcn_s_setprio(0);
    __builtin_amdgcn_sched_barrier(0);
    __builtin_amdgcn_s_barrier();
    __builtin_amdgcn_sched_barrier(0);
  }
  #pragma unroll
  for (int i = 0; i < 4; i++) {
    int m = m0 + wr * 64 + i * 16 + hi * 4;
    #pragma unroll
    for (int j = 0; j < 2; j++) {
      int n = n0 + wc * 32 + j * 16 + lo;
      float bv = bias[n];
      #pragma unroll
      for (int r = 0; r < 4; r++) {
        float v = acc[i][j][r] + bv;
        if (HAS_RES) {
          if (RES_BF16) v += bf2f(((const ushort_t*)res)[(size_t)(m + r) * N + n]);
          else          v += ((const float*)res)[(size_t)(m + r) * N + n];
        }
        if (RELU) v = fmaxf(v, 0.f);
        if (OUT_BF16) ((ushort_t*)Cm)[(size_t)(m + r) * N + n] = f2bf(v);
        else          ((float*)Cm)[(size_t)(m + r) * N + n] = v;
      }
    }
  }
}

// ---- stats: 4 waves x 32 k-rows, FOUR Q-tiles per barrier pair ----
__global__ __launch_bounds__(256) void attn_stats(
    const ushort_t* __restrict__ QKV, float* __restrict__ dinv) {
  int bid = blockIdx.x;
  int xcd = bid & 7, loc = (bid >> 3) & 31, half = bid >> 8;
  int bh = xcd * 4 + (loc & 3);
  int j = loc >> 2;
  int kb = half ? (15 - j) : j;
  int b = bh >> 4, h = bh & 15;
  int t = threadIdx.x, w = t >> 6, l = t & 63, l31 = l & 31, hi32 = l >> 5;
  __shared__ ushort_t Qs[2][4][2048];   // 32KB
  const ushort_t* Qb = QKV + (size_t)b * T_ * C3 + h * HS_;
  const ushort_t* Kb = Qb + C_;
  int k0w = kb * 128 + w * 32;
  short8 ka[4];
  #pragma unroll
  for (int c = 0; c < 4; c++)
    ka[c] = *(const short8*)(Kb + (size_t)(k0w + l31) * C3 + c * 16 + hi32 * 8);
  float s[16];
  #pragma unroll
  for (int r = 0; r < 16; r++) s[r] = 0.f;

  int qoff[4];
  #pragma unroll
  for (int c = 0; c < 4; c++)
    qoff[c] = l31 * 64 + ((c * 2 + hi32) ^ (l31 & 7)) * 8;

  int sr = t >> 3, slot = t & 7, su = slot ^ (sr & 7);
  const ushort_t* Qsrc = Qb + (size_t)sr * C3 + su * 8;
  int qt0 = kb * 4, cnt = 64 - qt0;      // multiple of 4
  int dqt = qt0 + w;

  #pragma unroll
  for (int sub = 0; sub < 4; sub++)
    gl_lds16(Qsrc + (size_t)(qt0 + sub) * 32 * C3, &Qs[0][sub][t * 8]);
  for (int i = 0; i < cnt; i += 4) {
    int buf = (i >> 2) & 1;
    if (i + 4 < cnt) {
      #pragma unroll
      for (int sub = 0; sub < 4; sub++)
        gl_lds16(Qsrc + (size_t)(qt0 + i + 4 + sub) * 32 * C3,
                 &Qs[buf ^ 1][sub][t * 8]);
      asm volatile("s_waitcnt vmcnt(4)");
    } else {
      asm volatile("s_waitcnt vmcnt(0)");
    }
    __builtin_amdgcn_s_barrier();
    __builtin_amdgcn_sched_barrier(0);
    #pragma unroll
    for (int sub = 0; sub < 4; sub++) {
      int qt = qt0 + i + sub;
      if (qt >= dqt) {
        const ushort_t* base = &Qs[buf][sub][0];
        short8 qf[4];
        #pragma unroll
        for (int c = 0; c < 4; c++)
          qf[c] = *(const short8*)(base + qoff[c]);
        __builtin_amdgcn_s_setprio(1);
        f32x16 d = {};
        #pragma unroll
        for (int c = 0; c < 4; c++) d = mfma32(ka[c], qf[c], d);
        __builtin_amdgcn_s_setprio(0);
        if (qt == dqt) {
          int qq = qt * 32 + l31;
          #pragma unroll
          for (int r = 0; r < 16; r++) {
            int k = k0w + (r & 3) + 8 * (r >> 2) + 4 * hi32;
            s[r] += (qq >= k) ? __builtin_amdgcn_exp2f(d[r]) : 0.f;
          }
        } else {
          #pragma unroll
          for (int r = 0; r < 16; r++) s[r] += __builtin_amdgcn_exp2f(d[r]);
        }
      }
    }
    __builtin_amdgcn_sched_barrier(0);
    __builtin_amdgcn_s_barrier();
    __builtin_amdgcn_sched_barrier(0);
  }
  #pragma unroll
  for (int off = 1; off < 32; off <<= 1)
    #pragma unroll
    for (int r = 0; r < 16; r++)
      s[r] += __shfl_xor(s[r], off);
  if (l31 == 0) {
    #pragma unroll
    for (int r = 0; r < 16; r++) {
      int k = k0w + (r & 3) + 8 * (r >> 2) + 4 * hi32;
      dinv[(size_t)bh * T_ + k] = 1.0f / s[r];
    }
  }
}

// ---- V' = V * dinv, per-head transpose to (bh, HS, T) ----
__global__ __launch_bounds__(256) void transpose_v(
    const ushort_t* __restrict__ QKV, const float* __restrict__ dinv,
    ushort_t* __restrict__ Vt) {
  int t0 = blockIdx.x * 64;
  int bh = blockIdx.y; int b = bh >> 4, h = bh & 15;
  __shared__ ushort_t tile[64][65];
  int tid = threadIdx.x;
  #pragma unroll
  for (int i = 0; i < 16; i++) {
    int idx = i * 256 + tid;
    int tt = idx >> 6, dd = idx & 63;
    float v = bf2f(QKV[(size_t)(b * T_ + t0 + tt) * C3 + 2 * C_ + h * HS_ + dd]);
    tile[tt][dd] = f2bf(v * dinv[(size_t)bh * T_ + t0 + tt]);
  }
  __syncthreads();
  #pragma unroll
  for (int i = 0; i < 16; i++) {
    int idx = i * 256 + tid;
    int dd = idx >> 6, tt = idx & 63;
    Vt[((size_t)(bh * HS_ + dd)) * T_ + t0 + tt] = tile[tt][dd];
  }
}

// ---- PV: 4 waves x 32 q-rows, FOUR k-tiles per barrier pair ----
__global__ __launch_bounds__(256) void attn_pv(
    const ushort_t* __restrict__ QKV, const ushort_t* __restrict__ Vt,
    ushort_t* __restrict__ att) {
  int bid = blockIdx.x;
  int xcd = bid & 7, loc = (bid >> 3) & 31, half = bid >> 8;
  int bh = xcd * 4 + (loc & 3);
  int j = loc >> 2;
  int qb = half ? j : (15 - j);
  int b = bh >> 4, h = bh & 15;
  int t = threadIdx.x, w = t >> 6, l = t & 63, l31 = l & 31, hi32 = l >> 5;
  __shared__ ushort_t KV[2][4][2][2048];   // 64KB
  const ushort_t* Qb = QKV + (size_t)b * T_ * C3 + h * HS_;
  const ushort_t* Kb = Qb + C_;
  const ushort_t* Vb = Vt + (size_t)bh * HS_ * T_;
  int q0w = qb * 128 + w * 32;
  short8 qf[4];
  #pragma unroll
  for (int c = 0; c < 4; c++)
    qf[c] = *(const short8*)(Qb + (size_t)(q0w + l31) * C3 + c * 16 + hi32 * 8);
  f32x16 o0 = {}, o1 = {};
  int nkt = qb * 4 + 4;
  int dkt = q0w >> 5;

  int koff[4], voff[4];
  #pragma unroll
  for (int c = 0; c < 4; c++)
    koff[c] = l31 * 64 + ((c * 2 + hi32) ^ (l31 & 7)) * 8;
  #pragma unroll
  for (int i = 0; i < 4; i++) {
    int u = (i & 1) * 4 + (i >> 1) * 2 + hi32;
    voff[i] = 2048 + l31 * 64 + (u ^ (l31 & 7)) * 8;
  }

  int sr = t >> 3, slot = t & 7, su = slot ^ (sr & 7);
  int vdh = su >> 2, vc2 = su & 3;
  const ushort_t* Ksrc = Kb + (size_t)sr * C3 + su * 8;
  const ushort_t* Vsrc = Vb + (size_t)(vdh * 32 + sr) * T_ + vc2 * 8;

  #pragma unroll
  for (int sub = 0; sub < 4; sub++) {
    gl_lds16(Ksrc + (size_t)sub * 32 * C3, &KV[0][sub][0][t * 8]);
    gl_lds16(Vsrc + sub * 32,              &KV[0][sub][1][t * 8]);
  }
  for (int kt = 0; kt < nkt; kt += 4) {
    int buf = (kt >> 2) & 1;
    if (kt + 4 < nkt) {
      #pragma unroll
      for (int sub = 0; sub < 4; sub++) {
        gl_lds16(Ksrc + (size_t)(kt + 4 + sub) * 32 * C3, &KV[buf ^ 1][sub][0][t * 8]);
        gl_lds16(Vsrc + (kt + 4 + sub) * 32,              &KV[buf ^ 1][sub][1][t * 8]);
      }
      asm volatile("s_waitcnt vmcnt(8)");
    } else {
      asm volatile("s_waitcnt vmcnt(0)");
    }
    __builtin_amdgcn_s_barrier();
    __builtin_amdgcn_sched_barrier(0);
    #pragma unroll
    for (int sub = 0; sub < 4; sub++) {
      int kts = kt + sub;
      if (kts <= dkt) {
        const ushort_t* base = &KV[buf][sub][0][0];
        short8 ka[4], vf[4];
        #pragma unroll
        for (int c = 0; c < 4; c++)
          ka[c] = *(const short8*)(base + koff[c]);
        #pragma unroll
        for (int i = 0; i < 4; i++)
          vf[i] = *(const short8*)(base + voff[i]);
        __builtin_amdgcn_s_setprio(1);
        f32x16 sacc = {};
        #pragma unroll
        for (int c = 0; c < 4; c++) sacc = mfma32(ka[c], qf[c], sacc);
        __builtin_amdgcn_s_setprio(0);
        float e[16];
        if (kts == dkt) {
          int qq = q0w + l31;
          #pragma unroll
          for (int r = 0; r < 16; r++) {
            int k = kts * 32 + (r & 3) + 8 * (r >> 2) + 4 * hi32;
            e[r] = (k <= qq) ? __builtin_amdgcn_exp2f(sacc[r]) : 0.f;
          }
        } else {
          #pragma unroll
          for (int r = 0; r < 16; r++) e[r] = __builtin_amdgcn_exp2f(sacc[r]);
        }
        unsigned u[8];
        #pragma unroll
        for (int j2 = 0; j2 < 8; j2++) u[j2] = pkhw(e[2 * j2], e[2 * j2 + 1]);
        pl32swap(u[0], u[2]); pl32swap(u[1], u[3]);
        pl32swap(u[4], u[6]); pl32swap(u[5], u[7]);
        short8 pa0 = mk8(u[0], u[1], u[2], u[3]);
        short8 pa1 = mk8(u[4], u[5], u[6], u[7]);
        __builtin_amdgcn_s_setprio(1);
        o0 = mfma32(pa0, vf[0], o0);
        o1 = mfma32(pa0, vf[1], o1);
        o0 = mfma32(pa1, vf[2], o0);
        o1 = mfma32(pa1, vf[3], o1);
        __builtin_amdgcn_s_setprio(0);
      }
    }
    __builtin_amdgcn_sched_barrier(0);
    __builtin_amdgcn_s_barrier();
    __builtin_amdgcn_sched_barrier(0);
  }

  #pragma unroll
  for (int r = 0; r < 16; r++) {
    int qq = q0w + (r & 3) + 8 * (r >> 2) + 4 * hi32;
    size_t base = (size_t)(b * T_ + qq) * C_ + h * HS_;
    att[base + l31]      = f2bf(o0[r]);
    att[base + 32 + l31] = f2bf(o1[r]);
  }
}

extern "C" void kernel_launch(void* const* d_in, const int* in_sizes, int n_in,
                              void* d_out, int out_size, void* d_ws, size_t ws_size,
                              hipStream_t stream) {
  const float* x   = (const float*)d_in[0];
  const float* Wq  = (const float*)d_in[1];
  const float* bq  = (const float*)d_in[2];
  const float* Wk  = (const float*)d_in[3];
  const float* bk  = (const float*)d_in[4];
  const float* Wv  = (const float*)d_in[5];
  const float* bv  = (const float*)d_in[6];
  const float* Wo  = (const float*)d_in[7];
  const float* bo  = (const float*)d_in[8];
  const float* g1  = (const float*)d_in[9];
  const float* b1  = (const float*)d_in[10];
  const float* g2  = (const float*)d_in[11];
  const float* b2  = (const float*)d_in[12];
  const float* W1  = (const float*)d_in[13];
  const float* bf1 = (const float*)d_in[14];
  const float* W2  = (const float*)d_in[15];
  const float* bf2 = (const float*)d_in[16];
  float* out = (float*)d_out;

  char* base = (char*)d_ws;
  const size_t MB = 1 << 20;
  ushort_t* QKVb  = (ushort_t*)(base);            // 24MB
  ushort_t* hb    = (ushort_t*)(base + 24 * MB);  // 8MB: LN1 out -> att
  ushort_t* Vt    = (ushort_t*)(base + 32 * MB);  // 8MB: V' -> f1b
  ushort_t* y     = (ushort_t*)(base + 40 * MB);  // 8MB (bf16 now)
  ushort_t* Wqkvt = (ushort_t*)(base + 56 * MB);  // 6MB
  ushort_t* Wot   = (ushort_t*)(base + 62 * MB);  // 2MB (Wo,W1,W2 contiguous)
  ushort_t* W1t   = (ushort_t*)(base + 64 * MB);
  ushort_t* W2t   = (ushort_t*)(base + 66 * MB);
  float*    bqkv  = (float*)   (base + 68 * MB);  // 12KB
  float*    dinv  = (float*)   (base + 68 * MB + 65536); // 256KB

  prep_weights<<<1537, 256, 0, stream>>>(Wq, Wk, Wv, Wo, W1, W2,
                                         bq, bk, bv, Wqkvt, Wot, bqkv);

  ln_bf16<<<NROWS, 256, 0, stream>>>(x, g1, b1, hb);

  gemm128q<<<768, 256, 0, stream>>>(hb, Wqkvt, bqkv, QKVb, NROWS, C3, C_);

  attn_stats<<<512, 256, 0, stream>>>(QKVb, dinv);
  transpose_v<<<dim3(T_ / 64, 32), 256, 0, stream>>>(QKVb, dinv, Vt);
  ushort_t* attb = hb;
  attn_pv<<<512, 256, 0, stream>>>(QKVb, Vt, attb);

  dim3 g64(C_ / 64, NROWS / 128);
  // y (bf16) = att @ Wo + bo + x(f32)
  gemm64<1,0,1,0><<<g64, 256, 0, stream>>>(attb, Wot, bo, x, y, NROWS, C_, C_);

  ushort_t* h2b = QKVb;
  ln_bf16_in16<<<NROWS, 256, 0, stream>>>(y, g2, b2, h2b);
  ushort_t* f1b = Vt;
  gemm64<1,1,0,0><<<g64, 256, 0, stream>>>(h2b, W1t, bf1, nullptr, f1b, NROWS, C_, C_);
  // out (f32) = f1 @ W2 + bf2 + y(bf16)
  gemm64<0,0,1,1><<<g64, 256, 0, stream>>>(f1b, W2t, bf2, y, out, NROWS, C_, C_);
}